// Round 1
// baseline (1884.699 us; speedup 1.0000x reference)
//
#include <hip/hip_runtime.h>
#include <math.h>

// Problem constants (B=4, Q=2048, KV=2048, D=512)
#define BATCH 4
#define QN    2048
#define KVN   2048
#define DN    512
#define U_TOT 15615          // int(Q * ln(KV))
#define NSEL  60             // int(8 * ln(Q))
#define NSPLIT 8             // U-splits for phase-1
#define S1SPLIT 8            // kv-splits for s1 = attn @ v
#define NUTILE 122           // ceil(U_TOT / 128)

// ---------------- Phase 1: partial max/sum of s_bar = q @ k_bar^T ----------------
#define BM 128
#define BN 128
#define BK 32

__global__ __launch_bounds__(256) void m_partial_kernel(
    const float* __restrict__ q, const float* __restrict__ k,
    const int* __restrict__ sidx, float* __restrict__ Pmax, float* __restrict__ Psum)
{
  __shared__ float a_s[BK][BM + 4];   // transposed: a_s[kk][row]
  __shared__ float b_s[BK][BN + 4];
  __shared__ int   si_s[BN];

  const int t  = threadIdx.x;
  const int tx = t & 15, ty = t >> 4;
  const int q0 = blockIdx.x * BM;
  const int b  = blockIdx.y;
  const int sp = blockIdx.z;

  const float* qb = q + ((size_t)b * QN + q0) * DN;
  const float* kb = k + (size_t)b * KVN * DN;
  const int*  sib = sidx + b * U_TOT;

  float tmax[8], tsum[8];
#pragma unroll
  for (int i = 0; i < 8; ++i) { tmax[i] = -INFINITY; tsum[i] = 0.f; }

  const int c4 = (t & 7) * 4;   // D-chunk column group (0,4,..,28)
  const int r0 = t >> 3;        // 0..31

  for (int ut = sp; ut < NUTILE; ut += NSPLIT) {
    const int u0 = ut * BN;
    __syncthreads();
    if (t < BN) {
      int u = u0 + t;
      si_s[t] = (u < U_TOT) ? sib[u] : 0;
    }
    __syncthreads();

    float acc[8][8];
#pragma unroll
    for (int i = 0; i < 8; ++i)
#pragma unroll
      for (int j = 0; j < 8; ++j) acc[i][j] = 0.f;

    for (int d0 = 0; d0 < DN; d0 += BK) {
      // stage q tile (128 x 32), transposed into LDS
#pragma unroll
      for (int rr = 0; rr < 4; ++rr) {
        int row = r0 + rr * 32;
        float4 vv = *reinterpret_cast<const float4*>(qb + (size_t)row * DN + d0 + c4);
        a_s[c4 + 0][row] = vv.x; a_s[c4 + 1][row] = vv.y;
        a_s[c4 + 2][row] = vv.z; a_s[c4 + 3][row] = vv.w;
      }
      // stage gathered k_bar tile (128 x 32), transposed
#pragma unroll
      for (int rr = 0; rr < 4; ++rr) {
        int row = r0 + rr * 32;
        float4 vv = *reinterpret_cast<const float4*>(kb + (size_t)si_s[row] * DN + d0 + c4);
        b_s[c4 + 0][row] = vv.x; b_s[c4 + 1][row] = vv.y;
        b_s[c4 + 2][row] = vv.z; b_s[c4 + 3][row] = vv.w;
      }
      __syncthreads();
#pragma unroll
      for (int kk = 0; kk < BK; ++kk) {
        float4 a0 = *reinterpret_cast<const float4*>(&a_s[kk][ty * 8]);
        float4 a1 = *reinterpret_cast<const float4*>(&a_s[kk][ty * 8 + 4]);
        float4 b0 = *reinterpret_cast<const float4*>(&b_s[kk][tx * 8]);
        float4 b1 = *reinterpret_cast<const float4*>(&b_s[kk][tx * 8 + 4]);
        float af[8] = {a0.x, a0.y, a0.z, a0.w, a1.x, a1.y, a1.z, a1.w};
        float bf[8] = {b0.x, b0.y, b0.z, b0.w, b1.x, b1.y, b1.z, b1.w};
#pragma unroll
        for (int i = 0; i < 8; ++i)
#pragma unroll
          for (int j = 0; j < 8; ++j)
            acc[i][j] = fmaf(af[i], bf[j], acc[i][j]);
      }
      __syncthreads();
    }

    // fold tile into per-thread running max/sum (mask u >= U_TOT)
#pragma unroll
    for (int j = 0; j < 8; ++j) {
      int u = u0 + tx * 8 + j;
      if (u < U_TOT) {
#pragma unroll
        for (int i = 0; i < 8; ++i) {
          tmax[i] = fmaxf(tmax[i], acc[i][j]);
          tsum[i] += acc[i][j];
        }
      }
    }
  }

  // cross-tx reduction (16 partials per row) via LDS, reusing a_s
  float* red = &a_s[0][0];   // needs 128*17 = 2176 floats (a_s has 4224)
  __syncthreads();
#pragma unroll
  for (int i = 0; i < 8; ++i) red[(ty * 8 + i) * 17 + tx] = tmax[i];
  __syncthreads();
  if (t < BM) {
    float m = red[t * 17];
    for (int x = 1; x < 16; ++x) m = fmaxf(m, red[t * 17 + x]);
    Pmax[((size_t)(sp * BATCH + b)) * QN + q0 + t] = m;
  }
  __syncthreads();
#pragma unroll
  for (int i = 0; i < 8; ++i) red[(ty * 8 + i) * 17 + tx] = tsum[i];
  __syncthreads();
  if (t < BM) {
    float s = 0.f;
    for (int x = 0; x < 16; ++x) s += red[t * 17 + x];
    Psum[((size_t)(sp * BATCH + b)) * QN + q0 + t] = s;
  }
}

// ---------------- Phase 2: combine splits, iterative top-60 (jax tie-break) ----------------
__global__ __launch_bounds__(256) void topk_kernel(
    const float* __restrict__ Pmax, const float* __restrict__ Psum, int* __restrict__ topidx)
{
  __shared__ float Ml[QN];
  __shared__ unsigned long long red[256];
  const int b = blockIdx.x;
  const int t = threadIdx.x;

  for (int qq = t; qq < QN; qq += 256) {
    float m = -INFINITY, s = 0.f;
    for (int sp = 0; sp < NSPLIT; ++sp) {
      m = fmaxf(m, Pmax[((size_t)(sp * BATCH + b)) * QN + qq]);
      s += Psum[((size_t)(sp * BATCH + b)) * QN + qq];
    }
    Ml[qq] = m - s * (1.0f / (float)U_TOT);
  }
  __syncthreads();

  for (int it = 0; it < NSEL; ++it) {
    unsigned long long best = 0ull;
    for (int qq = t; qq < QN; qq += 256) {
      unsigned int u = __float_as_uint(Ml[qq]);
      u = (u & 0x80000000u) ? ~u : (u | 0x80000000u);   // order-preserving map
      unsigned long long key = ((unsigned long long)u << 32) | (unsigned int)(QN - qq);
      if (key > best) best = key;
    }
    red[t] = best;
    __syncthreads();
    for (int off = 128; off > 0; off >>= 1) {
      if (t < off && red[t + off] > red[t]) red[t] = red[t + off];
      __syncthreads();
    }
    int qsel = QN - (int)(red[0] & 0xFFFFFFFFull);
    if (t == 0) {
      topidx[b * 64 + it] = qsel;
      Ml[qsel] = -INFINITY;
    }
    __syncthreads();
  }
}

// ---------------- gather q_bar (padded to 64 rows) ----------------
__global__ void gather_qbar_kernel(const float* __restrict__ q,
                                   const int* __restrict__ topidx, float* __restrict__ qbar)
{
  const int j = blockIdx.x;   // 0..63
  const int b = blockIdx.y;
  const int t = threadIdx.x;  // 128
  float4 val = make_float4(0.f, 0.f, 0.f, 0.f);
  if (j < NSEL) {
    int row = topidx[b * 64 + j];
    val = *reinterpret_cast<const float4*>(q + ((size_t)b * QN + row) * DN + t * 4);
  }
  *reinterpret_cast<float4*>(qbar + ((size_t)(b * 64 + j)) * DN + t * 4) = val;
}

// ---------------- scores = q_bar @ k^T (raw, unscaled) ----------------
#define SBM 64
#define SBN 64
#define SBK 32
__global__ __launch_bounds__(256) void scores_kernel(
    const float* __restrict__ qbar, const float* __restrict__ k, float* __restrict__ attn)
{
  __shared__ float a_s[SBK][SBM + 4];
  __shared__ float b_s[SBK][SBN + 4];
  const int t  = threadIdx.x;
  const int tx = t & 15, ty = t >> 4;
  const int kv0 = blockIdx.x * SBN;
  const int b   = blockIdx.y;
  const float* qb = qbar + (size_t)b * 64 * DN;
  const float* kb = k + (size_t)b * KVN * DN;

  float acc[4][4];
#pragma unroll
  for (int i = 0; i < 4; ++i)
#pragma unroll
    for (int j = 0; j < 4; ++j) acc[i][j] = 0.f;

  const int c4 = (t & 7) * 4;
  const int r0 = t >> 3;   // 0..31

  for (int d0 = 0; d0 < DN; d0 += SBK) {
#pragma unroll
    for (int rr = 0; rr < 2; ++rr) {
      int row = r0 + rr * 32;
      float4 av = *reinterpret_cast<const float4*>(qb + (size_t)row * DN + d0 + c4);
      a_s[c4 + 0][row] = av.x; a_s[c4 + 1][row] = av.y;
      a_s[c4 + 2][row] = av.z; a_s[c4 + 3][row] = av.w;
      float4 bv = *reinterpret_cast<const float4*>(kb + (size_t)(kv0 + row) * DN + d0 + c4);
      b_s[c4 + 0][row] = bv.x; b_s[c4 + 1][row] = bv.y;
      b_s[c4 + 2][row] = bv.z; b_s[c4 + 3][row] = bv.w;
    }
    __syncthreads();
#pragma unroll
    for (int kk = 0; kk < SBK; ++kk) {
      float4 av = *reinterpret_cast<const float4*>(&a_s[kk][ty * 4]);
      float4 bv = *reinterpret_cast<const float4*>(&b_s[kk][tx * 4]);
      float af[4] = {av.x, av.y, av.z, av.w};
      float bf[4] = {bv.x, bv.y, bv.z, bv.w};
#pragma unroll
      for (int i = 0; i < 4; ++i)
#pragma unroll
        for (int j = 0; j < 4; ++j)
          acc[i][j] = fmaf(af[i], bf[j], acc[i][j]);
    }
    __syncthreads();
  }

#pragma unroll
  for (int i = 0; i < 4; ++i) {
    int j = ty * 4 + i;
    if (j < NSEL) {
      float4 o = make_float4(acc[i][0], acc[i][1], acc[i][2], acc[i][3]);
      *reinterpret_cast<float4*>(attn + ((size_t)(b * NSEL + j)) * KVN + kv0 + tx * 4) = o;
    }
  }
}

// ---------------- softmax over 2048 keys per selected row ----------------
__global__ __launch_bounds__(256) void softmax_kernel(float* __restrict__ attn)
{
  __shared__ float buf[KVN];
  __shared__ float red[256];
  const int t = threadIdx.x;
  float* row = attn + (size_t)blockIdx.x * KVN;

  float m = -INFINITY;
  for (int i = t; i < KVN; i += 256) { float v = row[i]; buf[i] = v; m = fmaxf(m, v); }
  red[t] = m;
  __syncthreads();
  for (int off = 128; off > 0; off >>= 1) {
    if (t < off) red[t] = fmaxf(red[t], red[t + off]);
    __syncthreads();
  }
  m = red[0];
  __syncthreads();

  const float sc = 0.022097086912079608f;   // 1/sqrt(2048)
  float s = 0.f;
  for (int i = t; i < KVN; i += 256) { float e = __expf((buf[i] - m) * sc); buf[i] = e; s += e; }
  red[t] = s;
  __syncthreads();
  for (int off = 128; off > 0; off >>= 1) {
    if (t < off) red[t] += red[t + off];
    __syncthreads();
  }
  float inv = 1.f / red[0];
  for (int i = t; i < KVN; i += 256) row[i] = buf[i] * inv;
}

// ---------------- s1 partials = attn @ v over kv-splits ----------------
__global__ __launch_bounds__(256) void s1_partial_kernel(
    const float* __restrict__ attn, const float* __restrict__ v, float* __restrict__ part)
{
  __shared__ float a_s[NSEL][32];
  const int t    = threadIdx.x;
  const int dloc = t & 127;
  const int jg   = t >> 7;          // 0 or 1 (30 rows each)
  const int d0   = blockIdx.x * 128;
  const int b    = blockIdx.y;
  const int sp   = blockIdx.z;
  const int kvbase = sp * (KVN / S1SPLIT);   // 256 keys per split

  float acc[30];
#pragma unroll
  for (int i = 0; i < 30; ++i) acc[i] = 0.f;

  for (int kc = 0; kc < KVN / S1SPLIT; kc += 32) {
    __syncthreads();
    for (int x = t; x < NSEL * 32; x += 256) {
      int j = x >> 5, kk = x & 31;
      a_s[j][kk] = attn[((size_t)(b * NSEL + j)) * KVN + kvbase + kc + kk];
    }
    __syncthreads();
#pragma unroll 4
    for (int kk = 0; kk < 32; ++kk) {
      float vv = v[((size_t)b * KVN + kvbase + kc + kk) * DN + d0 + dloc];
#pragma unroll
      for (int jj = 0; jj < 30; ++jj)
        acc[jj] = fmaf(a_s[jg * 30 + jj][kk], vv, acc[jj]);
    }
  }
#pragma unroll
  for (int jj = 0; jj < 30; ++jj)
    part[((size_t)((sp * BATCH + b) * NSEL) + jg * 30 + jj) * DN + d0 + dloc] = acc[jj];
}

// ---------------- v mean (2-stage) ----------------
__global__ __launch_bounds__(256) void vmean_part_kernel(
    const float* __restrict__ v, float* __restrict__ vpart)
{
  const int t = threadIdx.x;
  const int c = blockIdx.x;   // 0..15
  const int b = blockIdx.y;
  const int kv0 = c * 128;
  for (int d = t; d < DN; d += 256) {
    float s = 0.f;
    for (int r = 0; r < 128; ++r) s += v[((size_t)b * KVN + kv0 + r) * DN + d];
    vpart[(size_t)(c * BATCH + b) * DN + d] = s;
  }
}

__global__ void vmean_combine_kernel(const float* __restrict__ vpart, float* __restrict__ vmean)
{
  int idx = blockIdx.x * 256 + threadIdx.x;   // 0..2047
  if (idx < BATCH * DN) {
    int b = idx / DN, d = idx % DN;
    float s = 0.f;
    for (int c = 0; c < 16; ++c) s += vpart[(size_t)(c * BATCH + b) * DN + d];
    vmean[idx] = s * (1.0f / (float)KVN);
  }
}

// ---------------- fill output with v-mean ----------------
__global__ __launch_bounds__(256) void fill_kernel(
    const float* __restrict__ vmean, float* __restrict__ out)
{
  size_t gid = (size_t)blockIdx.x * 256 + threadIdx.x;   // float4 index
  size_t e = gid * 4;
  int b = (int)(e >> 20);          // Q*D = 1<<20 per batch
  int d = (int)(e & (DN - 1));
  float4 mv = *reinterpret_cast<const float4*>(vmean + b * DN + d);
  *reinterpret_cast<float4*>(out + e) = mv;
}

// ---------------- combine s1 partials & scatter to selected rows ----------------
__global__ void scatter_kernel(const float* __restrict__ part,
                               const int* __restrict__ topidx, float* __restrict__ out)
{
  const int t = threadIdx.x;   // 128
  const int j = blockIdx.x;    // 0..59
  const int b = blockIdx.y;
  const int row = topidx[b * 64 + j];
  const int d = t * 4;
  float4 s = make_float4(0.f, 0.f, 0.f, 0.f);
  for (int sp = 0; sp < S1SPLIT; ++sp) {
    float4 p = *reinterpret_cast<const float4*>(
        part + ((size_t)((sp * BATCH + b) * NSEL) + j) * DN + d);
    s.x += p.x; s.y += p.y; s.z += p.z; s.w += p.w;
  }
  *reinterpret_cast<float4*>(out + ((size_t)b * QN + row) * DN + d) = s;
}

// ---------------- launcher ----------------
extern "C" void kernel_launch(void* const* d_in, const int* in_sizes, int n_in,
                              void* d_out, int out_size, void* d_ws, size_t ws_size,
                              hipStream_t stream) {
  const float* q    = (const float*)d_in[0];
  const float* k    = (const float*)d_in[1];
  const float* v    = (const float*)d_in[2];
  const int*   sidx = (const int*)d_in[3];
  float* out = (float*)d_out;
  float* ws  = (float*)d_ws;

  // workspace layout (floats)
  float* Pmax   = ws;                 // 8*4*2048   = 65536
  float* Psum   = ws + 65536;         // 65536
  int*   topidx = (int*)(ws + 131072);// 4*64 ints  = 256
  float* qbar   = ws + 131328;        // 4*64*512   = 131072
  float* attn   = ws + 262400;        // 4*60*2048  = 491520
  float* part   = ws + 753920;        // 8*4*60*512 = 983040
  float* vpart  = ws + 1736960;       // 16*4*512   = 32768
  float* vmean  = ws + 1769728;       // 4*512      = 2048
  // total = 1,771,776 floats ≈ 7.1 MB

  m_partial_kernel<<<dim3(QN / BM, BATCH, NSPLIT), 256, 0, stream>>>(q, k, sidx, Pmax, Psum);
  topk_kernel<<<dim3(BATCH), 256, 0, stream>>>(Pmax, Psum, topidx);
  gather_qbar_kernel<<<dim3(64, BATCH), 128, 0, stream>>>(q, topidx, qbar);
  scores_kernel<<<dim3(KVN / SBN, BATCH), 256, 0, stream>>>(qbar, k, attn);
  softmax_kernel<<<dim3(BATCH * NSEL), 256, 0, stream>>>(attn);
  s1_partial_kernel<<<dim3(4, BATCH, S1SPLIT), 256, 0, stream>>>(attn, v, part);
  vmean_part_kernel<<<dim3(16, BATCH), 256, 0, stream>>>(v, vpart);
  vmean_combine_kernel<<<dim3(8), 256, 0, stream>>>(vpart, vmean);
  fill_kernel<<<dim3(4096), 256, 0, stream>>>(vmean, out);
  scatter_kernel<<<dim3(NSEL, BATCH), 128, 0, stream>>>(part, topidx, out);
}

// Round 2
// 1028.495 us; speedup vs baseline: 1.8325x; 1.8325x over previous
//
#include <hip/hip_runtime.h>
#include <math.h>

// Problem constants (B=4, Q=2048, KV=2048, D=512)
#define BATCH 4
#define QN    2048
#define KVN   2048
#define DN    512
#define U_TOT 15615          // int(Q * ln(KV))
#define NSEL  60             // int(8 * ln(Q))
#define NSPLIT 8             // U-splits for phase-1
#define SP2   16             // NSPLIT * 2 (two n-half waves write separate partials)
#define S1SPLIT 8            // kv-splits for s1 = attn @ v
#define NUTILE 122           // ceil(U_TOT / 128)

typedef __attribute__((ext_vector_type(8))) short bf16x8;
typedef __attribute__((ext_vector_type(4))) float f32x4;

// ---------------- helpers ----------------
__device__ __forceinline__ unsigned short f2bf(float f) {
  unsigned u = __float_as_uint(f);
  unsigned r = (u + 0x7fffu + ((u >> 16) & 1u)) >> 16;   // RNE
  return (unsigned short)r;
}
__device__ __forceinline__ float bf2f(unsigned short h) {
  return __uint_as_float(((unsigned)h) << 16);
}

__device__ __forceinline__ void gld16(const void* g, void* l) {
  __builtin_amdgcn_global_load_lds(
      (const __attribute__((address_space(1))) unsigned int*)g,
      (__attribute__((address_space(3))) unsigned int*)l, 16, 0, 0);
}

// ---------------- split fp32 -> bf16 hi/lo ----------------
__global__ __launch_bounds__(256) void split_kernel(
    const float* __restrict__ in, unsigned short* __restrict__ hi,
    unsigned short* __restrict__ lo)
{
  int i = blockIdx.x * 256 + threadIdx.x;   // float4 index; grid covers exactly n/4
  float4 f = reinterpret_cast<const float4*>(in)[i];
  ushort4 h, l;
  h.x = f2bf(f.x); l.x = f2bf(f.x - bf2f(h.x));
  h.y = f2bf(f.y); l.y = f2bf(f.y - bf2f(h.y));
  h.z = f2bf(f.z); l.z = f2bf(f.z - bf2f(h.z));
  h.w = f2bf(f.w); l.w = f2bf(f.w - bf2f(h.w));
  reinterpret_cast<ushort4*>(hi)[i] = h;
  reinterpret_cast<ushort4*>(lo)[i] = l;
}

// ---------------- Phase 1: MFMA partial max/sum of s_bar = q @ k_bar^T ----------------
// 128x128 tile, BK=32 bf16, 3 MFMA passes (hh, hl, lh). 256 thr = 4 waves,
// each wave owns a 64x64 quadrant (4x4 grid of 16x16x32 MFMAs).
__global__ __launch_bounds__(256) void m_mfma_kernel(
    const unsigned short* __restrict__ qh, const unsigned short* __restrict__ ql,
    const unsigned short* __restrict__ kh, const unsigned short* __restrict__ kl,
    const int* __restrict__ sidx, float* __restrict__ Pmax, float* __restrict__ Psum)
{
  __shared__ unsigned short Ah[128 * 32];
  __shared__ unsigned short Al[128 * 32];
  __shared__ unsigned short Bh[128 * 32];
  __shared__ unsigned short Bl[128 * 32];
  __shared__ int si_s[128];

  const int t = threadIdx.x;
  const int w = t >> 6;          // wave 0..3
  const int L = t & 63;          // lane
  const int mbase = (w & 1) * 64;
  const int nbase = (w >> 1) * 64;

  // XCD-locality swizzle: bid bits = [0]=sp_lo, [1:2]=b, [3:6]=qi, [7:8]=sp_hi
  const int bid = blockIdx.x;
  const int b   = (bid >> 1) & 3;
  const int qi  = (bid >> 3) & 15;
  const int sp  = ((bid >> 7) << 1) | (bid & 1);
  const int q0  = qi * 128;

  const int* sib = sidx + b * U_TOT;

  // staging element offsets (q is contiguous; row = idx>>2, col = (idx&3)*8)
  const size_t qoff0 = ((size_t)(b * QN) + q0 + (t >> 2)) * DN + (size_t)((t & 3) * 8);
  const size_t qoff1 = qoff0 + (size_t)64 * DN;

  float tmax[4][4], tsum[4][4];
#pragma unroll
  for (int i = 0; i < 4; ++i)
#pragma unroll
    for (int r = 0; r < 4; ++r) { tmax[i][r] = -INFINITY; tsum[i][r] = 0.f; }

  const int lm = L & 15;          // frag row/col lane index
  const int lk = (L >> 4) * 8;    // k-chunk

  for (int ut = sp; ut < NUTILE; ut += NSPLIT) {
    const int u0 = ut * 128;
    __syncthreads();
    if (t < 128) si_s[t] = (u0 + t < U_TOT) ? sib[u0 + t] : 0;
    __syncthreads();

    const size_t koff0 = ((size_t)(b * KVN) + si_s[t >> 2]) * DN + (size_t)((t & 3) * 8);
    const size_t koff1 = ((size_t)(b * KVN) + si_s[64 + (t >> 2)]) * DN + (size_t)((t & 3) * 8);

    f32x4 acc[4][4];   // [nf][mf]
#pragma unroll
    for (int nf = 0; nf < 4; ++nf)
#pragma unroll
      for (int mf = 0; mf < 4; ++mf) {
        acc[nf][mf][0] = 0.f; acc[nf][mf][1] = 0.f;
        acc[nf][mf][2] = 0.f; acc[nf][mf][3] = 0.f;
      }

    for (int d0 = 0; d0 < DN; d0 += 32) {
      gld16(qh + qoff0 + d0, &Ah[t * 8]);
      gld16(qh + qoff1 + d0, &Ah[(t + 256) * 8]);
      gld16(ql + qoff0 + d0, &Al[t * 8]);
      gld16(ql + qoff1 + d0, &Al[(t + 256) * 8]);
      gld16(kh + koff0 + d0, &Bh[t * 8]);
      gld16(kh + koff1 + d0, &Bh[(t + 256) * 8]);
      gld16(kl + koff0 + d0, &Bl[t * 8]);
      gld16(kl + koff1 + d0, &Bl[(t + 256) * 8]);
      __syncthreads();

      bf16x8 ah[4], al[4];
#pragma unroll
      for (int mf = 0; mf < 4; ++mf) {
        const int m = mbase + mf * 16 + lm;
        ah[mf] = *reinterpret_cast<const bf16x8*>(&Ah[m * 32 + lk]);
        al[mf] = *reinterpret_cast<const bf16x8*>(&Al[m * 32 + lk]);
      }
#pragma unroll
      for (int nf = 0; nf < 4; ++nf) {
        const int n = nbase + nf * 16 + lm;
        bf16x8 bh = *reinterpret_cast<const bf16x8*>(&Bh[n * 32 + lk]);
        bf16x8 bl = *reinterpret_cast<const bf16x8*>(&Bl[n * 32 + lk]);
#pragma unroll
        for (int mf = 0; mf < 4; ++mf) {
          acc[nf][mf] = __builtin_amdgcn_mfma_f32_16x16x32_bf16(ah[mf], bh, acc[nf][mf], 0, 0, 0);
          acc[nf][mf] = __builtin_amdgcn_mfma_f32_16x16x32_bf16(ah[mf], bl, acc[nf][mf], 0, 0, 0);
          acc[nf][mf] = __builtin_amdgcn_mfma_f32_16x16x32_bf16(al[mf], bh, acc[nf][mf], 0, 0, 0);
        }
      }
      __syncthreads();
    }

    // fold tile into running max/sum; C/D map: n = lane&15, m = (lane>>4)*4 + reg
#pragma unroll
    for (int nf = 0; nf < 4; ++nf) {
      const int u = u0 + nbase + nf * 16 + lm;
      if (u < U_TOT) {
#pragma unroll
        for (int mf = 0; mf < 4; ++mf)
#pragma unroll
          for (int r = 0; r < 4; ++r) {
            const float v = acc[nf][mf][r];
            tmax[mf][r] = fmaxf(tmax[mf][r], v);
            tsum[mf][r] += v;
          }
      }
    }
  }

  // reduce across the 16 lanes of each column group, write per-(sp, n-half) partials
  const size_t spi = (size_t)((sp * 2 + (w >> 1)) * BATCH + b);
#pragma unroll
  for (int mf = 0; mf < 4; ++mf)
#pragma unroll
    for (int r = 0; r < 4; ++r) {
      float m = tmax[mf][r];
      float s = tsum[mf][r];
#pragma unroll
      for (int o = 1; o < 16; o <<= 1) {
        m = fmaxf(m, __shfl_xor(m, o));
        s += __shfl_xor(s, o);
      }
      if (lm == 0) {
        const int qrow = q0 + mbase + mf * 16 + (L >> 4) * 4 + r;
        Pmax[spi * QN + qrow] = m;
        Psum[spi * QN + qrow] = s;
      }
    }
}

// ---------------- Phase 2: combine splits, iterative top-60 (jax tie-break) ----------------
__global__ __launch_bounds__(256) void topk_kernel(
    const float* __restrict__ Pmax, const float* __restrict__ Psum, int* __restrict__ topidx)
{
  __shared__ float Ml[QN];
  __shared__ unsigned long long red[256];
  const int b = blockIdx.x;
  const int t = threadIdx.x;

  for (int qq = t; qq < QN; qq += 256) {
    float m = -INFINITY, s = 0.f;
    for (int sp = 0; sp < SP2; ++sp) {
      m = fmaxf(m, Pmax[((size_t)(sp * BATCH + b)) * QN + qq]);
      s += Psum[((size_t)(sp * BATCH + b)) * QN + qq];
    }
    Ml[qq] = m - s * (1.0f / (float)U_TOT);
  }
  __syncthreads();

  for (int it = 0; it < NSEL; ++it) {
    unsigned long long best = 0ull;
    for (int qq = t; qq < QN; qq += 256) {
      unsigned int u = __float_as_uint(Ml[qq]);
      u = (u & 0x80000000u) ? ~u : (u | 0x80000000u);   // order-preserving map
      unsigned long long key = ((unsigned long long)u << 32) | (unsigned int)(QN - qq);
      if (key > best) best = key;
    }
    red[t] = best;
    __syncthreads();
    for (int off = 128; off > 0; off >>= 1) {
      if (t < off && red[t + off] > red[t]) red[t] = red[t + off];
      __syncthreads();
    }
    int qsel = QN - (int)(red[0] & 0xFFFFFFFFull);
    if (t == 0) {
      topidx[b * 64 + it] = qsel;
      Ml[qsel] = -INFINITY;
    }
    __syncthreads();
  }
}

// ---------------- gather q_bar (padded to 64 rows) ----------------
__global__ void gather_qbar_kernel(const float* __restrict__ q,
                                   const int* __restrict__ topidx, float* __restrict__ qbar)
{
  const int j = blockIdx.x;   // 0..63
  const int b = blockIdx.y;
  const int t = threadIdx.x;  // 128
  float4 val = make_float4(0.f, 0.f, 0.f, 0.f);
  if (j < NSEL) {
    int row = topidx[b * 64 + j];
    val = *reinterpret_cast<const float4*>(q + ((size_t)b * QN + row) * DN + t * 4);
  }
  *reinterpret_cast<float4*>(qbar + ((size_t)(b * 64 + j)) * DN + t * 4) = val;
}

// ---------------- scores = q_bar @ k^T (raw, unscaled) ----------------
#define SBM 64
#define SBN 64
#define SBK 32
__global__ __launch_bounds__(256) void scores_kernel(
    const float* __restrict__ qbar, const float* __restrict__ k, float* __restrict__ attn)
{
  __shared__ float a_s[SBK][SBM + 4];
  __shared__ float b_s[SBK][SBN + 4];
  const int t  = threadIdx.x;
  const int tx = t & 15, ty = t >> 4;
  const int kv0 = blockIdx.x * SBN;
  const int b   = blockIdx.y;
  const float* qb = qbar + (size_t)b * 64 * DN;
  const float* kb = k + (size_t)b * KVN * DN;

  float acc[4][4];
#pragma unroll
  for (int i = 0; i < 4; ++i)
#pragma unroll
    for (int j = 0; j < 4; ++j) acc[i][j] = 0.f;

  const int c4 = (t & 7) * 4;
  const int r0 = t >> 3;   // 0..31

  for (int d0 = 0; d0 < DN; d0 += SBK) {
#pragma unroll
    for (int rr = 0; rr < 2; ++rr) {
      int row = r0 + rr * 32;
      float4 av = *reinterpret_cast<const float4*>(qb + (size_t)row * DN + d0 + c4);
      a_s[c4 + 0][row] = av.x; a_s[c4 + 1][row] = av.y;
      a_s[c4 + 2][row] = av.z; a_s[c4 + 3][row] = av.w;
      float4 bv = *reinterpret_cast<const float4*>(kb + (size_t)(kv0 + row) * DN + d0 + c4);
      b_s[c4 + 0][row] = bv.x; b_s[c4 + 1][row] = bv.y;
      b_s[c4 + 2][row] = bv.z; b_s[c4 + 3][row] = bv.w;
    }
    __syncthreads();
#pragma unroll
    for (int kk = 0; kk < SBK; ++kk) {
      float4 av = *reinterpret_cast<const float4*>(&a_s[kk][ty * 4]);
      float4 bv = *reinterpret_cast<const float4*>(&b_s[kk][tx * 4]);
      float af[4] = {av.x, av.y, av.z, av.w};
      float bf[4] = {bv.x, bv.y, bv.z, bv.w};
#pragma unroll
      for (int i = 0; i < 4; ++i)
#pragma unroll
        for (int j = 0; j < 4; ++j)
          acc[i][j] = fmaf(af[i], bf[j], acc[i][j]);
    }
    __syncthreads();
  }

#pragma unroll
  for (int i = 0; i < 4; ++i) {
    int j = ty * 4 + i;
    if (j < NSEL) {
      float4 o = make_float4(acc[i][0], acc[i][1], acc[i][2], acc[i][3]);
      *reinterpret_cast<float4*>(attn + ((size_t)(b * NSEL + j)) * KVN + kv0 + tx * 4) = o;
    }
  }
}

// ---------------- softmax over 2048 keys per selected row ----------------
__global__ __launch_bounds__(256) void softmax_kernel(float* __restrict__ attn)
{
  __shared__ float buf[KVN];
  __shared__ float red[256];
  const int t = threadIdx.x;
  float* row = attn + (size_t)blockIdx.x * KVN;

  float m = -INFINITY;
  for (int i = t; i < KVN; i += 256) { float v = row[i]; buf[i] = v; m = fmaxf(m, v); }
  red[t] = m;
  __syncthreads();
  for (int off = 128; off > 0; off >>= 1) {
    if (t < off) red[t] = fmaxf(red[t], red[t + off]);
    __syncthreads();
  }
  m = red[0];
  __syncthreads();

  const float sc = 0.022097086912079608f;   // 1/sqrt(2048)
  float s = 0.f;
  for (int i = t; i < KVN; i += 256) { float e = __expf((buf[i] - m) * sc); buf[i] = e; s += e; }
  red[t] = s;
  __syncthreads();
  for (int off = 128; off > 0; off >>= 1) {
    if (t < off) red[t] += red[t + off];
    __syncthreads();
  }
  float inv = 1.f / red[0];
  for (int i = t; i < KVN; i += 256) row[i] = buf[i] * inv;
}

// ---------------- s1 partials = attn @ v over kv-splits ----------------
__global__ __launch_bounds__(256) void s1_partial_kernel(
    const float* __restrict__ attn, const float* __restrict__ v, float* __restrict__ part)
{
  __shared__ float a_s[NSEL][32];
  const int t    = threadIdx.x;
  const int dloc = t & 127;
  const int jg   = t >> 7;          // 0 or 1 (30 rows each)
  const int d0   = blockIdx.x * 128;
  const int b    = blockIdx.y;
  const int sp   = blockIdx.z;
  const int kvbase = sp * (KVN / S1SPLIT);   // 256 keys per split

  float acc[30];
#pragma unroll
  for (int i = 0; i < 30; ++i) acc[i] = 0.f;

  for (int kc = 0; kc < KVN / S1SPLIT; kc += 32) {
    __syncthreads();
    for (int x = t; x < NSEL * 32; x += 256) {
      int j = x >> 5, kk = x & 31;
      a_s[j][kk] = attn[((size_t)(b * NSEL + j)) * KVN + kvbase + kc + kk];
    }
    __syncthreads();
#pragma unroll 4
    for (int kk = 0; kk < 32; ++kk) {
      float vv = v[((size_t)b * KVN + kvbase + kc + kk) * DN + d0 + dloc];
#pragma unroll
      for (int jj = 0; jj < 30; ++jj)
        acc[jj] = fmaf(a_s[jg * 30 + jj][kk], vv, acc[jj]);
    }
  }
#pragma unroll
  for (int jj = 0; jj < 30; ++jj)
    part[((size_t)((sp * BATCH + b) * NSEL) + jg * 30 + jj) * DN + d0 + dloc] = acc[jj];
}

// ---------------- v mean (2-stage) ----------------
__global__ __launch_bounds__(256) void vmean_part_kernel(
    const float* __restrict__ v, float* __restrict__ vpart)
{
  const int t = threadIdx.x;
  const int c = blockIdx.x;   // 0..15
  const int b = blockIdx.y;
  const int kv0 = c * 128;
  for (int d = t; d < DN; d += 256) {
    float s = 0.f;
    for (int r = 0; r < 128; ++r) s += v[((size_t)b * KVN + kv0 + r) * DN + d];
    vpart[(size_t)(c * BATCH + b) * DN + d] = s;
  }
}

__global__ void vmean_combine_kernel(const float* __restrict__ vpart, float* __restrict__ vmean)
{
  int idx = blockIdx.x * 256 + threadIdx.x;   // 0..2047
  if (idx < BATCH * DN) {
    int b = idx / DN, d = idx % DN;
    float s = 0.f;
    for (int c = 0; c < 16; ++c) s += vpart[(size_t)(c * BATCH + b) * DN + d];
    vmean[idx] = s * (1.0f / (float)KVN);
  }
}

// ---------------- fill output with v-mean ----------------
__global__ __launch_bounds__(256) void fill_kernel(
    const float* __restrict__ vmean, float* __restrict__ out)
{
  size_t gid = (size_t)blockIdx.x * 256 + threadIdx.x;   // float4 index
  size_t e = gid * 4;
  int b = (int)(e >> 20);          // Q*D = 1<<20 per batch
  int d = (int)(e & (DN - 1));
  float4 mv = *reinterpret_cast<const float4*>(vmean + b * DN + d);
  *reinterpret_cast<float4*>(out + e) = mv;
}

// ---------------- combine s1 partials & scatter to selected rows ----------------
__global__ void scatter_kernel(const float* __restrict__ part,
                               const int* __restrict__ topidx, float* __restrict__ out)
{
  const int t = threadIdx.x;   // 128
  const int j = blockIdx.x;    // 0..59
  const int b = blockIdx.y;
  const int row = topidx[b * 64 + j];
  const int d = t * 4;
  float4 s = make_float4(0.f, 0.f, 0.f, 0.f);
  for (int sp = 0; sp < S1SPLIT; ++sp) {
    float4 p = *reinterpret_cast<const float4*>(
        part + ((size_t)((sp * BATCH + b) * NSEL) + j) * DN + d);
    s.x += p.x; s.y += p.y; s.z += p.z; s.w += p.w;
  }
  *reinterpret_cast<float4*>(out + ((size_t)b * QN + row) * DN + d) = s;
}

// ---------------- launcher ----------------
extern "C" void kernel_launch(void* const* d_in, const int* in_sizes, int n_in,
                              void* d_out, int out_size, void* d_ws, size_t ws_size,
                              hipStream_t stream) {
  const float* q    = (const float*)d_in[0];
  const float* k    = (const float*)d_in[1];
  const float* v    = (const float*)d_in[2];
  const int*   sidx = (const int*)d_in[3];
  float* out = (float*)d_out;
  char*  W   = (char*)d_ws;

  // workspace layout (bytes)
  const size_t NEL = (size_t)BATCH * QN * DN;           // 4,194,304 elements
  unsigned short* qh = (unsigned short*)W;              // 8 MB
  unsigned short* ql = qh + NEL;                        // 8 MB
  unsigned short* kh = ql + NEL;                        // 8 MB
  unsigned short* kl = kh + NEL;                        // 8 MB -> ends at 32 MB
  float* Pmax   = (float*)(W + 4 * NEL * sizeof(unsigned short));  // 16*4*2048 = 131072 fl
  float* Psum   = Pmax + SP2 * BATCH * QN;              // 131072 fl
  int*   topidx = (int*)(Psum + SP2 * BATCH * QN);      // 256 ints
  float* qbar   = (float*)(topidx + 256);               // 131072 fl
  float* attn   = qbar + BATCH * 64 * DN;               // 491520 fl
  float* part   = attn + (size_t)BATCH * NSEL * KVN;    // 983040 fl
  float* vpart  = part + (size_t)S1SPLIT * BATCH * NSEL * DN;  // 32768 fl
  float* vmean  = vpart + 16 * BATCH * DN;              // 2048 fl
  // total ~= 39.6 MB

  split_kernel<<<dim3(4096), 256, 0, stream>>>(q, qh, ql);
  split_kernel<<<dim3(4096), 256, 0, stream>>>(k, kh, kl);
  m_mfma_kernel<<<dim3(512), 256, 0, stream>>>(qh, ql, kh, kl, sidx, Pmax, Psum);
  topk_kernel<<<dim3(BATCH), 256, 0, stream>>>(Pmax, Psum, topidx);
  gather_qbar_kernel<<<dim3(64, BATCH), 128, 0, stream>>>(q, topidx, qbar);
  scores_kernel<<<dim3(KVN / SBN, BATCH), 256, 0, stream>>>(qbar, k, attn);
  softmax_kernel<<<dim3(BATCH * NSEL), 256, 0, stream>>>(attn);
  s1_partial_kernel<<<dim3(4, BATCH, S1SPLIT), 256, 0, stream>>>(attn, v, part);
  vmean_part_kernel<<<dim3(16, BATCH), 256, 0, stream>>>(v, vpart);
  vmean_combine_kernel<<<dim3(8), 256, 0, stream>>>(vpart, vmean);
  fill_kernel<<<dim3(4096), 256, 0, stream>>>(vmean, out);
  scatter_kernel<<<dim3(NSEL, BATCH), 128, 0, stream>>>(part, topidx, out);
}

// Round 3
// 571.570 us; speedup vs baseline: 3.2974x; 1.7994x over previous
//
#include <hip/hip_runtime.h>
#include <math.h>

// Problem constants (B=4, Q=2048, KV=2048, D=512)
#define BATCH 4
#define QN    2048
#define KVN   2048
#define DN    512
#define U_TOT 15615          // int(Q * ln(KV))
#define NSEL  60             // int(8 * ln(Q))
#define NSLOT 32             // 16 j-tiles x 2 n-half waves
#define S1SPLIT 8            // kv-splits for s1 = attn @ v

typedef __attribute__((ext_vector_type(8))) short bf16x8;
typedef __attribute__((ext_vector_type(4))) float f32x4;

// ---------------- helpers ----------------
__device__ __forceinline__ unsigned short f2bf(float f) {
  unsigned u = __float_as_uint(f);
  unsigned r = (u + 0x7fffu + ((u >> 16) & 1u)) >> 16;   // RNE
  return (unsigned short)r;
}
__device__ __forceinline__ float bf2f(unsigned short h) {
  return __uint_as_float(((unsigned)h) << 16);
}
__device__ __forceinline__ void gld16(const void* g, void* l) {
  __builtin_amdgcn_global_load_lds(
      (const __attribute__((address_space(1))) unsigned int*)g,
      (__attribute__((address_space(3))) unsigned int*)l, 16, 0, 0);
}
__device__ __forceinline__ unsigned long long shfl_xor_u64(unsigned long long v, int o) {
  unsigned lo = (unsigned)v, hi = (unsigned)(v >> 32);
  lo = (unsigned)__shfl_xor((int)lo, o);
  hi = (unsigned)__shfl_xor((int)hi, o);
  return ((unsigned long long)hi << 32) | lo;
}

// ---------------- split fp32 -> bf16 hi/lo ----------------
__global__ __launch_bounds__(256) void split_kernel(
    const float* __restrict__ in, unsigned short* __restrict__ hi,
    unsigned short* __restrict__ lo)
{
  int i = blockIdx.x * 256 + threadIdx.x;   // float4 index; grid covers exactly n/4
  float4 f = reinterpret_cast<const float4*>(in)[i];
  ushort4 h, l;
  h.x = f2bf(f.x); l.x = f2bf(f.x - bf2f(h.x));
  h.y = f2bf(f.y); l.y = f2bf(f.y - bf2f(h.y));
  h.z = f2bf(f.z); l.z = f2bf(f.z - bf2f(h.z));
  h.w = f2bf(f.w); l.w = f2bf(f.w - bf2f(h.w));
  reinterpret_cast<ushort4*>(hi)[i] = h;
  reinterpret_cast<ushort4*>(lo)[i] = l;
}

// ---------------- counts histogram: cnt[b][j] = multiplicity of key j ----------------
__global__ __launch_bounds__(256) void count_kernel(
    const int* __restrict__ sidx, float* __restrict__ cnt)
{
  __shared__ int h[KVN];
  const int b = blockIdx.x, t = threadIdx.x;
  for (int i = t; i < KVN; i += 256) h[i] = 0;
  __syncthreads();
  for (int i = t; i < U_TOT; i += 256) atomicAdd(&h[sidx[b * U_TOT + i]], 1);
  __syncthreads();
  for (int i = t; i < KVN; i += 256) cnt[b * KVN + i] = (float)h[i];
}

// ---------------- Phase 1: dense S = q @ k^T with fused masked-max / weighted-sum ----
// 512 blocks; each: one 128-j tile x two 128-q tiles, K=512 in BK=32, 3 MFMA passes.
__global__ __launch_bounds__(256) void s_mfma_kernel(
    const unsigned short* __restrict__ qh, const unsigned short* __restrict__ ql,
    const unsigned short* __restrict__ kh, const unsigned short* __restrict__ kl,
    const float* __restrict__ cnt, float* __restrict__ Pmax, float* __restrict__ Psum)
{
  __shared__ unsigned short Ah[128 * 32];
  __shared__ unsigned short Al[128 * 32];
  __shared__ unsigned short Bh[128 * 32];
  __shared__ unsigned short Bl[128 * 32];
  __shared__ float cnt_s[128];

  const int t = threadIdx.x;
  const int w = t >> 6;          // wave 0..3
  const int L = t & 63;
  const int mbase = (w & 1) * 64;
  const int nbase = (w >> 1) * 64;
  const int lm = L & 15;
  const int lk = (L >> 4) * 8;

  // XCD swizzle: xcd = bid&7 -> batch = xcd>>1, j-half = xcd&1
  const int bid = blockIdx.x;
  const int xcd = bid & 7;
  const int idx = bid >> 3;      // 0..63
  const int b   = xcd >> 1;
  const int ji  = (xcd & 1) * 8 + (idx >> 3);   // 0..15
  const int qi0 = (idx & 7) * 2;                // q-tile pair
  const int j0  = ji * 128;

  if (t < 128) cnt_s[t] = cnt[b * KVN + j0 + t];

  const size_t koff0 = ((size_t)(b * KVN) + j0 + (t >> 2)) * DN + (size_t)((t & 3) * 8);
  const size_t koff1 = koff0 + (size_t)64 * DN;

  for (int qq = 0; qq < 2; ++qq) {
    const int q0 = (qi0 + qq) * 128;
    const size_t qoff0 = ((size_t)(b * QN) + q0 + (t >> 2)) * DN + (size_t)((t & 3) * 8);
    const size_t qoff1 = qoff0 + (size_t)64 * DN;

    f32x4 acc[4][4];   // [nf][mf]
#pragma unroll
    for (int nf = 0; nf < 4; ++nf)
#pragma unroll
      for (int mf = 0; mf < 4; ++mf) {
        acc[nf][mf][0] = 0.f; acc[nf][mf][1] = 0.f;
        acc[nf][mf][2] = 0.f; acc[nf][mf][3] = 0.f;
      }

    for (int d0 = 0; d0 < DN; d0 += 32) {
      __syncthreads();   // LDS reads from previous step done
      gld16(qh + qoff0 + d0, &Ah[t * 8]);
      gld16(qh + qoff1 + d0, &Ah[(t + 256) * 8]);
      gld16(ql + qoff0 + d0, &Al[t * 8]);
      gld16(ql + qoff1 + d0, &Al[(t + 256) * 8]);
      gld16(kh + koff0 + d0, &Bh[t * 8]);
      gld16(kh + koff1 + d0, &Bh[(t + 256) * 8]);
      gld16(kl + koff0 + d0, &Bl[t * 8]);
      gld16(kl + koff1 + d0, &Bl[(t + 256) * 8]);
      __syncthreads();

      bf16x8 ah[4], al[4];
#pragma unroll
      for (int mf = 0; mf < 4; ++mf) {
        const int m = mbase + mf * 16 + lm;
        ah[mf] = *reinterpret_cast<const bf16x8*>(&Ah[m * 32 + lk]);
        al[mf] = *reinterpret_cast<const bf16x8*>(&Al[m * 32 + lk]);
      }
#pragma unroll
      for (int nf = 0; nf < 4; ++nf) {
        const int n = nbase + nf * 16 + lm;
        bf16x8 bh = *reinterpret_cast<const bf16x8*>(&Bh[n * 32 + lk]);
        bf16x8 bl = *reinterpret_cast<const bf16x8*>(&Bl[n * 32 + lk]);
#pragma unroll
        for (int mf = 0; mf < 4; ++mf) {
          acc[nf][mf] = __builtin_amdgcn_mfma_f32_16x16x32_bf16(ah[mf], bh, acc[nf][mf], 0, 0, 0);
          acc[nf][mf] = __builtin_amdgcn_mfma_f32_16x16x32_bf16(ah[mf], bl, acc[nf][mf], 0, 0, 0);
          acc[nf][mf] = __builtin_amdgcn_mfma_f32_16x16x32_bf16(al[mf], bh, acc[nf][mf], 0, 0, 0);
        }
      }
    }

    // fused epilogue: masked max + count-weighted sum over this j-tile
    // C/D map: j(col) = lane&15, q(row) = (lane>>4)*4 + reg  [m89-verified]
    float mx[4][4], wsm[4][4];
#pragma unroll
    for (int mf = 0; mf < 4; ++mf)
#pragma unroll
      for (int r = 0; r < 4; ++r) { mx[mf][r] = -INFINITY; wsm[mf][r] = 0.f; }

#pragma unroll
    for (int nf = 0; nf < 4; ++nf) {
      const float c = cnt_s[nbase + nf * 16 + lm];
      const bool has = (c > 0.f);
#pragma unroll
      for (int mf = 0; mf < 4; ++mf)
#pragma unroll
        for (int r = 0; r < 4; ++r) {
          const float v = acc[nf][mf][r];
          if (has) mx[mf][r] = fmaxf(mx[mf][r], v);
          wsm[mf][r] = fmaf(c, v, wsm[mf][r]);
        }
    }

    const size_t spi = (size_t)((ji * 2 + (w >> 1)) * BATCH + b);
#pragma unroll
    for (int mf = 0; mf < 4; ++mf)
#pragma unroll
      for (int r = 0; r < 4; ++r) {
        float m = mx[mf][r], s = wsm[mf][r];
#pragma unroll
        for (int o = 1; o < 16; o <<= 1) {
          m = fmaxf(m, __shfl_xor(m, o));
          s += __shfl_xor(s, o);
        }
        if (lm == 0) {
          const int qrow = q0 + mbase + mf * 16 + (L >> 4) * 4 + r;
          Pmax[spi * QN + qrow] = m;
          Psum[spi * QN + qrow] = s;
        }
      }
  }
}

// ---------------- Phase 2: combine slots, iterative top-60 (jax tie-break) ----------
// one wave per batch, keys fully in registers
__global__ __launch_bounds__(64) void topk_kernel(
    const float* __restrict__ Pmax, const float* __restrict__ Psum, int* __restrict__ topidx)
{
  const int b = blockIdx.x;
  const int L = threadIdx.x;
  unsigned long long key[32];
#pragma unroll
  for (int s = 0; s < 32; ++s) {
    const int qq = s * 64 + L;
    float m = -INFINITY, sm = 0.f;
    for (int p = 0; p < NSLOT; ++p) {
      m = fmaxf(m, Pmax[((size_t)(p * BATCH + b)) * QN + qq]);
      sm += Psum[((size_t)(p * BATCH + b)) * QN + qq];
    }
    const float M = m - sm * (1.0f / (float)U_TOT);
    unsigned u = __float_as_uint(M);
    u = (u & 0x80000000u) ? ~u : (u | 0x80000000u);   // order-preserving map
    key[s] = ((unsigned long long)u << 32) | (unsigned)(QN - qq);
  }
  for (int it = 0; it < NSEL; ++it) {
    unsigned long long best = key[0];
#pragma unroll
    for (int s = 1; s < 32; ++s) best = (key[s] > best) ? key[s] : best;
    for (int o = 1; o < 64; o <<= 1) {
      unsigned long long oth = shfl_xor_u64(best, o);
      best = (oth > best) ? oth : best;
    }
    const int qsel = QN - (int)(best & 0xFFFFFFFFull);
    if (L == 0) topidx[b * 64 + it] = qsel;
    const int slot = qsel >> 6;
    const bool own = ((qsel & 63) == L);
#pragma unroll
    for (int s = 0; s < 32; ++s)
      if (own && s == slot) key[s] = 0ull;
  }
}

// ---------------- gather q_bar (padded to 64 rows) ----------------
__global__ void gather_qbar_kernel(const float* __restrict__ q,
                                   const int* __restrict__ topidx, float* __restrict__ qbar)
{
  const int j = blockIdx.x;   // 0..63
  const int b = blockIdx.y;
  const int t = threadIdx.x;  // 128
  float4 val = make_float4(0.f, 0.f, 0.f, 0.f);
  if (j < NSEL) {
    int row = topidx[b * 64 + j];
    val = *reinterpret_cast<const float4*>(q + ((size_t)b * QN + row) * DN + t * 4);
  }
  *reinterpret_cast<float4*>(qbar + ((size_t)(b * 64 + j)) * DN + t * 4) = val;
}

// ---------------- scores = q_bar @ k^T (raw, unscaled, fp32) ----------------
#define SBM 64
#define SBN 64
#define SBK 32
__global__ __launch_bounds__(256) void scores_kernel(
    const float* __restrict__ qbar, const float* __restrict__ k, float* __restrict__ attn)
{
  __shared__ float a_s[SBK][SBM + 4];
  __shared__ float b_s[SBK][SBN + 4];
  const int t  = threadIdx.x;
  const int tx = t & 15, ty = t >> 4;
  const int kv0 = blockIdx.x * SBN;
  const int b   = blockIdx.y;
  const float* qb = qbar + (size_t)b * 64 * DN;
  const float* kb = k + (size_t)b * KVN * DN;

  float acc[4][4];
#pragma unroll
  for (int i = 0; i < 4; ++i)
#pragma unroll
    for (int j = 0; j < 4; ++j) acc[i][j] = 0.f;

  const int c4 = (t & 7) * 4;
  const int r0 = t >> 3;   // 0..31

  for (int d0 = 0; d0 < DN; d0 += SBK) {
#pragma unroll
    for (int rr = 0; rr < 2; ++rr) {
      int row = r0 + rr * 32;
      float4 av = *reinterpret_cast<const float4*>(qb + (size_t)row * DN + d0 + c4);
      a_s[c4 + 0][row] = av.x; a_s[c4 + 1][row] = av.y;
      a_s[c4 + 2][row] = av.z; a_s[c4 + 3][row] = av.w;
      float4 bv = *reinterpret_cast<const float4*>(kb + (size_t)(kv0 + row) * DN + d0 + c4);
      b_s[c4 + 0][row] = bv.x; b_s[c4 + 1][row] = bv.y;
      b_s[c4 + 2][row] = bv.z; b_s[c4 + 3][row] = bv.w;
    }
    __syncthreads();
#pragma unroll
    for (int kk = 0; kk < SBK; ++kk) {
      float4 av = *reinterpret_cast<const float4*>(&a_s[kk][ty * 4]);
      float4 bv = *reinterpret_cast<const float4*>(&b_s[kk][tx * 4]);
      float af[4] = {av.x, av.y, av.z, av.w};
      float bf[4] = {bv.x, bv.y, bv.z, bv.w};
#pragma unroll
      for (int i = 0; i < 4; ++i)
#pragma unroll
        for (int j = 0; j < 4; ++j)
          acc[i][j] = fmaf(af[i], bf[j], acc[i][j]);
    }
    __syncthreads();
  }

#pragma unroll
  for (int i = 0; i < 4; ++i) {
    int j = ty * 4 + i;
    if (j < NSEL) {
      float4 o = make_float4(acc[i][0], acc[i][1], acc[i][2], acc[i][3]);
      *reinterpret_cast<float4*>(attn + ((size_t)(b * NSEL + j)) * KVN + kv0 + tx * 4) = o;
    }
  }
}

// ---------------- softmax over 2048 keys per selected row ----------------
__global__ __launch_bounds__(256) void softmax_kernel(float* __restrict__ attn)
{
  __shared__ float buf[KVN];
  __shared__ float red[256];
  const int t = threadIdx.x;
  float* row = attn + (size_t)blockIdx.x * KVN;

  float m = -INFINITY;
  for (int i = t; i < KVN; i += 256) { float v = row[i]; buf[i] = v; m = fmaxf(m, v); }
  red[t] = m;
  __syncthreads();
  for (int off = 128; off > 0; off >>= 1) {
    if (t < off) red[t] = fmaxf(red[t], red[t + off]);
    __syncthreads();
  }
  m = red[0];
  __syncthreads();

  const float sc = 0.022097086912079608f;   // 1/sqrt(2048)
  float s = 0.f;
  for (int i = t; i < KVN; i += 256) { float e = __expf((buf[i] - m) * sc); buf[i] = e; s += e; }
  red[t] = s;
  __syncthreads();
  for (int off = 128; off > 0; off >>= 1) {
    if (t < off) red[t] += red[t + off];
    __syncthreads();
  }
  float inv = 1.f / red[0];
  for (int i = t; i < KVN; i += 256) row[i] = buf[i] * inv;
}

// ---------------- s1 partials = attn @ v over kv-splits ----------------
__global__ __launch_bounds__(256) void s1_partial_kernel(
    const float* __restrict__ attn, const float* __restrict__ v, float* __restrict__ part)
{
  __shared__ float a_s[NSEL][32];
  const int t    = threadIdx.x;
  const int dloc = t & 127;
  const int jg   = t >> 7;          // 0 or 1 (30 rows each)
  const int d0   = blockIdx.x * 128;
  const int b    = blockIdx.y;
  const int sp   = blockIdx.z;
  const int kvbase = sp * (KVN / S1SPLIT);   // 256 keys per split

  float acc[30];
#pragma unroll
  for (int i = 0; i < 30; ++i) acc[i] = 0.f;

  for (int kc = 0; kc < KVN / S1SPLIT; kc += 32) {
    __syncthreads();
    for (int x = t; x < NSEL * 32; x += 256) {
      int j = x >> 5, kk = x & 31;
      a_s[j][kk] = attn[((size_t)(b * NSEL + j)) * KVN + kvbase + kc + kk];
    }
    __syncthreads();
#pragma unroll 4
    for (int kk = 0; kk < 32; ++kk) {
      float vv = v[((size_t)b * KVN + kvbase + kc + kk) * DN + d0 + dloc];
#pragma unroll
      for (int jj = 0; jj < 30; ++jj)
        acc[jj] = fmaf(a_s[jg * 30 + jj][kk], vv, acc[jj]);
    }
  }
#pragma unroll
  for (int jj = 0; jj < 30; ++jj)
    part[((size_t)((sp * BATCH + b) * NSEL) + jg * 30 + jj) * DN + d0 + dloc] = acc[jj];
}

// ---------------- v mean (2-stage) ----------------
__global__ __launch_bounds__(256) void vmean_part_kernel(
    const float* __restrict__ v, float* __restrict__ vpart)
{
  const int t = threadIdx.x;
  const int c = blockIdx.x;   // 0..15
  const int b = blockIdx.y;
  const int kv0 = c * 128;
  for (int d = t; d < DN; d += 256) {
    float s = 0.f;
    for (int r = 0; r < 128; ++r) s += v[((size_t)b * KVN + kv0 + r) * DN + d];
    vpart[(size_t)(c * BATCH + b) * DN + d] = s;
  }
}

__global__ void vmean_combine_kernel(const float* __restrict__ vpart, float* __restrict__ vmean)
{
  int idx = blockIdx.x * 256 + threadIdx.x;   // 0..2047
  if (idx < BATCH * DN) {
    int b = idx / DN, d = idx % DN;
    float s = 0.f;
    for (int c = 0; c < 16; ++c) s += vpart[(size_t)(c * BATCH + b) * DN + d];
    vmean[idx] = s * (1.0f / (float)KVN);
  }
}

// ---------------- fill output with v-mean ----------------
__global__ __launch_bounds__(256) void fill_kernel(
    const float* __restrict__ vmean, float* __restrict__ out)
{
  size_t gid = (size_t)blockIdx.x * 256 + threadIdx.x;   // float4 index
  size_t e = gid * 4;
  int b = (int)(e >> 20);          // Q*D = 1<<20 per batch
  int d = (int)(e & (DN - 1));
  float4 mv = *reinterpret_cast<const float4*>(vmean + b * DN + d);
  *reinterpret_cast<float4*>(out + e) = mv;
}

// ---------------- combine s1 partials & scatter to selected rows ----------------
__global__ void scatter_kernel(const float* __restrict__ part,
                               const int* __restrict__ topidx, float* __restrict__ out)
{
  const int t = threadIdx.x;   // 128
  const int j = blockIdx.x;    // 0..59
  const int b = blockIdx.y;
  const int row = topidx[b * 64 + j];
  const int d = t * 4;
  float4 s = make_float4(0.f, 0.f, 0.f, 0.f);
  for (int sp = 0; sp < S1SPLIT; ++sp) {
    float4 p = *reinterpret_cast<const float4*>(
        part + ((size_t)((sp * BATCH + b) * NSEL) + j) * DN + d);
    s.x += p.x; s.y += p.y; s.z += p.z; s.w += p.w;
  }
  *reinterpret_cast<float4*>(out + ((size_t)b * QN + row) * DN + d) = s;
}

// ---------------- launcher ----------------
extern "C" void kernel_launch(void* const* d_in, const int* in_sizes, int n_in,
                              void* d_out, int out_size, void* d_ws, size_t ws_size,
                              hipStream_t stream) {
  const float* q    = (const float*)d_in[0];
  const float* k    = (const float*)d_in[1];
  const float* v    = (const float*)d_in[2];
  const int*   sidx = (const int*)d_in[3];
  float* out = (float*)d_out;
  char*  W   = (char*)d_ws;

  // region A [0, 32 MB): bf16 splits (dead after s_mfma_kernel)
  const size_t NEL = (size_t)BATCH * QN * DN;   // 4,194,304
  unsigned short* qh = (unsigned short*)W;
  unsigned short* ql = qh + NEL;
  unsigned short* kh = ql + NEL;
  unsigned short* kl = kh + NEL;

  // region B [32 MB, ~34.1 MB): live across phase boundary
  char* W2 = W + 4 * NEL * sizeof(unsigned short);
  float* cnt    = (float*)W2;                         // 32 KB
  float* Pmax   = (float*)(W2 + 32768);               // 1 MB
  float* Psum   = (float*)(W2 + 32768 + 1048576);     // 1 MB
  int*   topidx = (int*)(W2 + 32768 + 2097152);       // 1 KB

  // post-phase-1 buffers aliased into region A (splits are dead by then)
  float* qbar  = (float*)W;                 // 512 KB
  float* attn  = (float*)(W + 524288);      // 1.875 MB
  float* part  = (float*)(W + 2490368);     // 3.75 MB
  float* vpart = (float*)(W + 6422528);     // 128 KB
  float* vmean = (float*)(W + 6553600);     // 8 KB

  split_kernel<<<dim3(4096), 256, 0, stream>>>(q, qh, ql);
  split_kernel<<<dim3(4096), 256, 0, stream>>>(k, kh, kl);
  count_kernel<<<dim3(BATCH), 256, 0, stream>>>(sidx, cnt);
  s_mfma_kernel<<<dim3(512), 256, 0, stream>>>(qh, ql, kh, kl, cnt, Pmax, Psum);
  topk_kernel<<<dim3(BATCH), 64, 0, stream>>>(Pmax, Psum, topidx);
  gather_qbar_kernel<<<dim3(64, BATCH), 128, 0, stream>>>(q, topidx, qbar);
  scores_kernel<<<dim3(KVN / SBN, BATCH), 256, 0, stream>>>(qbar, k, attn);
  softmax_kernel<<<dim3(BATCH * NSEL), 256, 0, stream>>>(attn);
  s1_partial_kernel<<<dim3(4, BATCH, S1SPLIT), 256, 0, stream>>>(attn, v, part);
  vmean_part_kernel<<<dim3(16, BATCH), 256, 0, stream>>>(v, vpart);
  vmean_combine_kernel<<<dim3(8), 256, 0, stream>>>(vpart, vmean);
  fill_kernel<<<dim3(4096), 256, 0, stream>>>(vmean, out);
  scatter_kernel<<<dim3(NSEL, BATCH), 128, 0, stream>>>(part, topidx, out);
}

// Round 4
// 401.065 us; speedup vs baseline: 4.6992x; 1.4251x over previous
//
#include <hip/hip_runtime.h>
#include <math.h>

// Problem constants (B=4, Q=2048, KV=2048, D=512)
#define BATCH 4
#define QN    2048
#define KVN   2048
#define DN    512
#define U_TOT 15615          // int(Q * ln(KV))
#define NSEL  60             // int(8 * ln(Q))
#define NSLOT 32             // 16 j-tiles x 2 n-half waves
#define S1SPLIT 8            // kv-splits for s1 = attn @ v

typedef __attribute__((ext_vector_type(8))) short bf16x8;
typedef __attribute__((ext_vector_type(4))) float f32x4;

// ---------------- helpers ----------------
__device__ __forceinline__ unsigned short f2bf(float f) {
  unsigned u = __float_as_uint(f);
  unsigned r = (u + 0x7fffu + ((u >> 16) & 1u)) >> 16;   // RNE
  return (unsigned short)r;
}
__device__ __forceinline__ float bf2f(unsigned short h) {
  return __uint_as_float(((unsigned)h) << 16);
}
__device__ __forceinline__ void gld16(const void* g, void* l) {
  __builtin_amdgcn_global_load_lds(
      (const __attribute__((address_space(1))) unsigned int*)g,
      (__attribute__((address_space(3))) unsigned int*)l, 16, 0, 0);
}
__device__ __forceinline__ unsigned long long shfl_xor_u64(unsigned long long v, int o) {
  unsigned lo = (unsigned)v, hi = (unsigned)(v >> 32);
  lo = (unsigned)__shfl_xor((int)lo, o);
  hi = (unsigned)__shfl_xor((int)hi, o);
  return ((unsigned long long)hi << 32) | lo;
}

// ---------------- split fp32 -> bf16 hi/lo ----------------
__global__ __launch_bounds__(256) void split_kernel(
    const float* __restrict__ in, unsigned short* __restrict__ hi,
    unsigned short* __restrict__ lo)
{
  int i = blockIdx.x * 256 + threadIdx.x;   // float4 index; grid covers exactly n/4
  float4 f = reinterpret_cast<const float4*>(in)[i];
  ushort4 h, l;
  h.x = f2bf(f.x); l.x = f2bf(f.x - bf2f(h.x));
  h.y = f2bf(f.y); l.y = f2bf(f.y - bf2f(h.y));
  h.z = f2bf(f.z); l.z = f2bf(f.z - bf2f(h.z));
  h.w = f2bf(f.w); l.w = f2bf(f.w - bf2f(h.w));
  reinterpret_cast<ushort4*>(hi)[i] = h;
  reinterpret_cast<ushort4*>(lo)[i] = l;
}

// ---------------- counts histogram: cnt[b][j] = multiplicity of key j ----------------
__global__ __launch_bounds__(256) void count_kernel(
    const int* __restrict__ sidx, float* __restrict__ cnt)
{
  __shared__ int h[KVN];
  const int b = blockIdx.x, t = threadIdx.x;
  for (int i = t; i < KVN; i += 256) h[i] = 0;
  __syncthreads();
  for (int i = t; i < U_TOT; i += 256) atomicAdd(&h[sidx[b * U_TOT + i]], 1);
  __syncthreads();
  for (int i = t; i < KVN; i += 256) cnt[b * KVN + i] = (float)h[i];
}

// ---------------- Phase 1: dense S = q @ k^T with fused masked-max / weighted-sum ----
// 512 blocks; each: one 128-j tile x two 128-q tiles, K=512 in BK=32, 3 MFMA passes.
__global__ __launch_bounds__(256) void s_mfma_kernel(
    const unsigned short* __restrict__ qh, const unsigned short* __restrict__ ql,
    const unsigned short* __restrict__ kh, const unsigned short* __restrict__ kl,
    const float* __restrict__ cnt, float* __restrict__ Pmax, float* __restrict__ Psum)
{
  __shared__ unsigned short Ah[128 * 32];
  __shared__ unsigned short Al[128 * 32];
  __shared__ unsigned short Bh[128 * 32];
  __shared__ unsigned short Bl[128 * 32];
  __shared__ float cnt_s[128];

  const int t = threadIdx.x;
  const int w = t >> 6;          // wave 0..3
  const int L = t & 63;
  const int mbase = (w & 1) * 64;
  const int nbase = (w >> 1) * 64;
  const int lm = L & 15;
  const int lk = (L >> 4) * 8;

  // XCD swizzle: xcd = bid&7 -> batch = xcd>>1, j-half = xcd&1
  const int bid = blockIdx.x;
  const int xcd = bid & 7;
  const int idx = bid >> 3;      // 0..63
  const int b   = xcd >> 1;
  const int ji  = (xcd & 1) * 8 + (idx >> 3);   // 0..15
  const int qi0 = (idx & 7) * 2;                // q-tile pair
  const int j0  = ji * 128;

  if (t < 128) cnt_s[t] = cnt[b * KVN + j0 + t];

  const size_t koff0 = ((size_t)(b * KVN) + j0 + (t >> 2)) * DN + (size_t)((t & 3) * 8);
  const size_t koff1 = koff0 + (size_t)64 * DN;

  for (int qq = 0; qq < 2; ++qq) {
    const int q0 = (qi0 + qq) * 128;
    const size_t qoff0 = ((size_t)(b * QN) + q0 + (t >> 2)) * DN + (size_t)((t & 3) * 8);
    const size_t qoff1 = qoff0 + (size_t)64 * DN;

    f32x4 acc[4][4];   // [nf][mf]
#pragma unroll
    for (int nf = 0; nf < 4; ++nf)
#pragma unroll
      for (int mf = 0; mf < 4; ++mf) {
        acc[nf][mf][0] = 0.f; acc[nf][mf][1] = 0.f;
        acc[nf][mf][2] = 0.f; acc[nf][mf][3] = 0.f;
      }

    for (int d0 = 0; d0 < DN; d0 += 32) {
      __syncthreads();   // LDS reads from previous step done
      gld16(qh + qoff0 + d0, &Ah[t * 8]);
      gld16(qh + qoff1 + d0, &Ah[(t + 256) * 8]);
      gld16(ql + qoff0 + d0, &Al[t * 8]);
      gld16(ql + qoff1 + d0, &Al[(t + 256) * 8]);
      gld16(kh + koff0 + d0, &Bh[t * 8]);
      gld16(kh + koff1 + d0, &Bh[(t + 256) * 8]);
      gld16(kl + koff0 + d0, &Bl[t * 8]);
      gld16(kl + koff1 + d0, &Bl[(t + 256) * 8]);
      __syncthreads();

      bf16x8 ah[4], al[4];
#pragma unroll
      for (int mf = 0; mf < 4; ++mf) {
        const int m = mbase + mf * 16 + lm;
        ah[mf] = *reinterpret_cast<const bf16x8*>(&Ah[m * 32 + lk]);
        al[mf] = *reinterpret_cast<const bf16x8*>(&Al[m * 32 + lk]);
      }
#pragma unroll
      for (int nf = 0; nf < 4; ++nf) {
        const int n = nbase + nf * 16 + lm;
        bf16x8 bh = *reinterpret_cast<const bf16x8*>(&Bh[n * 32 + lk]);
        bf16x8 bl = *reinterpret_cast<const bf16x8*>(&Bl[n * 32 + lk]);
#pragma unroll
        for (int mf = 0; mf < 4; ++mf) {
          acc[nf][mf] = __builtin_amdgcn_mfma_f32_16x16x32_bf16(ah[mf], bh, acc[nf][mf], 0, 0, 0);
          acc[nf][mf] = __builtin_amdgcn_mfma_f32_16x16x32_bf16(ah[mf], bl, acc[nf][mf], 0, 0, 0);
          acc[nf][mf] = __builtin_amdgcn_mfma_f32_16x16x32_bf16(al[mf], bh, acc[nf][mf], 0, 0, 0);
        }
      }
    }

    // fused epilogue: masked max + count-weighted sum over this j-tile
    // C/D map: j(col) = lane&15, q(row) = (lane>>4)*4 + reg  [m89-verified]
    float mx[4][4], wsm[4][4];
#pragma unroll
    for (int mf = 0; mf < 4; ++mf)
#pragma unroll
      for (int r = 0; r < 4; ++r) { mx[mf][r] = -INFINITY; wsm[mf][r] = 0.f; }

#pragma unroll
    for (int nf = 0; nf < 4; ++nf) {
      const float c = cnt_s[nbase + nf * 16 + lm];
      const bool has = (c > 0.f);
#pragma unroll
      for (int mf = 0; mf < 4; ++mf)
#pragma unroll
        for (int r = 0; r < 4; ++r) {
          const float v = acc[nf][mf][r];
          if (has) mx[mf][r] = fmaxf(mx[mf][r], v);
          wsm[mf][r] = fmaf(c, v, wsm[mf][r]);
        }
    }

    const size_t spi = (size_t)((ji * 2 + (w >> 1)) * BATCH + b);
#pragma unroll
    for (int mf = 0; mf < 4; ++mf)
#pragma unroll
      for (int r = 0; r < 4; ++r) {
        float m = mx[mf][r], s = wsm[mf][r];
#pragma unroll
        for (int o = 1; o < 16; o <<= 1) {
          m = fmaxf(m, __shfl_xor(m, o));
          s += __shfl_xor(s, o);
        }
        if (lm == 0) {
          const int qrow = q0 + mbase + mf * 16 + (L >> 4) * 4 + r;
          Pmax[spi * QN + qrow] = m;
          Psum[spi * QN + qrow] = s;
        }
      }
  }
}

// ---------------- Phase 2a: wide combine of the 32 partial slots -> M[b][q] --------
__global__ __launch_bounds__(256) void combine_kernel(
    const float* __restrict__ Pmax, const float* __restrict__ Psum, float* __restrict__ M)
{
  const int g = blockIdx.x * 256 + threadIdx.x;   // 0 .. BATCH*QN-1
  const int b = g >> 11;                          // QN = 2048
  const int qq = g & (QN - 1);
  float m = -INFINITY, s = 0.f;
#pragma unroll 4
  for (int p = 0; p < NSLOT; ++p) {
    m = fmaxf(m, Pmax[((size_t)(p * BATCH + b)) * QN + qq]);
    s += Psum[((size_t)(p * BATCH + b)) * QN + qq];
  }
  M[g] = m - s * (1.0f / (float)U_TOT);
}

// ---------------- Phase 2b: iterative top-60 (jax tie-break), 1 wave/batch --------
__global__ __launch_bounds__(64) void select_kernel(
    const float* __restrict__ M, int* __restrict__ topidx)
{
  const int b = blockIdx.x;
  const int L = threadIdx.x;
  unsigned long long key[32];
#pragma unroll
  for (int s = 0; s < 32; ++s) {
    const int qq = s * 64 + L;
    unsigned u = __float_as_uint(M[b * QN + qq]);
    u = (u & 0x80000000u) ? ~u : (u | 0x80000000u);   // order-preserving map
    key[s] = ((unsigned long long)u << 32) | (unsigned)(QN - qq);
  }
  for (int it = 0; it < NSEL; ++it) {
    unsigned long long best = key[0];
#pragma unroll
    for (int s = 1; s < 32; ++s) best = (key[s] > best) ? key[s] : best;
    for (int o = 1; o < 64; o <<= 1) {
      unsigned long long oth = shfl_xor_u64(best, o);
      best = (oth > best) ? oth : best;
    }
    const int qsel = QN - (int)(best & 0xFFFFFFFFull);
    if (L == 0) topidx[b * 64 + it] = qsel;
    const int slot = qsel >> 6;
    const bool own = ((qsel & 63) == L);
#pragma unroll
    for (int s = 0; s < 32; ++s)
      if (own && s == slot) key[s] = 0ull;
  }
}

// ---------------- gather q_bar (padded to 64 rows) ----------------
__global__ void gather_qbar_kernel(const float* __restrict__ q,
                                   const int* __restrict__ topidx, float* __restrict__ qbar)
{
  const int j = blockIdx.x;   // 0..63
  const int b = blockIdx.y;
  const int t = threadIdx.x;  // 128
  float4 val = make_float4(0.f, 0.f, 0.f, 0.f);
  if (j < NSEL) {
    int row = topidx[b * 64 + j];
    val = *reinterpret_cast<const float4*>(q + ((size_t)b * QN + row) * DN + t * 4);
  }
  *reinterpret_cast<float4*>(qbar + ((size_t)(b * 64 + j)) * DN + t * 4) = val;
}

// ---------------- scores = q_bar @ k^T (raw, unscaled, fp32) ----------------
#define SBM 64
#define SBN 64
#define SBK 32
__global__ __launch_bounds__(256) void scores_kernel(
    const float* __restrict__ qbar, const float* __restrict__ k, float* __restrict__ attn)
{
  __shared__ float a_s[SBK][SBM + 4];
  __shared__ float b_s[SBK][SBN + 4];
  const int t  = threadIdx.x;
  const int tx = t & 15, ty = t >> 4;
  const int kv0 = blockIdx.x * SBN;
  const int b   = blockIdx.y;
  const float* qb = qbar + (size_t)b * 64 * DN;
  const float* kb = k + (size_t)b * KVN * DN;

  float acc[4][4];
#pragma unroll
  for (int i = 0; i < 4; ++i)
#pragma unroll
    for (int j = 0; j < 4; ++j) acc[i][j] = 0.f;

  const int c4 = (t & 7) * 4;
  const int r0 = t >> 3;   // 0..31

  for (int d0 = 0; d0 < DN; d0 += SBK) {
#pragma unroll
    for (int rr = 0; rr < 2; ++rr) {
      int row = r0 + rr * 32;
      float4 av = *reinterpret_cast<const float4*>(qb + (size_t)row * DN + d0 + c4);
      a_s[c4 + 0][row] = av.x; a_s[c4 + 1][row] = av.y;
      a_s[c4 + 2][row] = av.z; a_s[c4 + 3][row] = av.w;
      float4 bv = *reinterpret_cast<const float4*>(kb + (size_t)(kv0 + row) * DN + d0 + c4);
      b_s[c4 + 0][row] = bv.x; b_s[c4 + 1][row] = bv.y;
      b_s[c4 + 2][row] = bv.z; b_s[c4 + 3][row] = bv.w;
    }
    __syncthreads();
#pragma unroll
    for (int kk = 0; kk < SBK; ++kk) {
      float4 av = *reinterpret_cast<const float4*>(&a_s[kk][ty * 4]);
      float4 bv = *reinterpret_cast<const float4*>(&b_s[kk][tx * 4]);
      float af[4] = {av.x, av.y, av.z, av.w};
      float bf[4] = {bv.x, bv.y, bv.z, bv.w};
#pragma unroll
      for (int i = 0; i < 4; ++i)
#pragma unroll
        for (int j = 0; j < 4; ++j)
          acc[i][j] = fmaf(af[i], bf[j], acc[i][j]);
    }
    __syncthreads();
  }

#pragma unroll
  for (int i = 0; i < 4; ++i) {
    int j = ty * 4 + i;
    if (j < NSEL) {
      float4 o = make_float4(acc[i][0], acc[i][1], acc[i][2], acc[i][3]);
      *reinterpret_cast<float4*>(attn + ((size_t)(b * NSEL + j)) * KVN + kv0 + tx * 4) = o;
    }
  }
}

// ---------------- softmax over 2048 keys per selected row ----------------
__global__ __launch_bounds__(256) void softmax_kernel(float* __restrict__ attn)
{
  __shared__ float buf[KVN];
  __shared__ float red[256];
  const int t = threadIdx.x;
  float* row = attn + (size_t)blockIdx.x * KVN;

  float m = -INFINITY;
  for (int i = t; i < KVN; i += 256) { float v = row[i]; buf[i] = v; m = fmaxf(m, v); }
  red[t] = m;
  __syncthreads();
  for (int off = 128; off > 0; off >>= 1) {
    if (t < off) red[t] = fmaxf(red[t], red[t + off]);
    __syncthreads();
  }
  m = red[0];
  __syncthreads();

  const float sc = 0.022097086912079608f;   // 1/sqrt(2048)
  float s = 0.f;
  for (int i = t; i < KVN; i += 256) { float e = __expf((buf[i] - m) * sc); buf[i] = e; s += e; }
  red[t] = s;
  __syncthreads();
  for (int off = 128; off > 0; off >>= 1) {
    if (t < off) red[t] += red[t + off];
    __syncthreads();
  }
  float inv = 1.f / red[0];
  for (int i = t; i < KVN; i += 256) row[i] = buf[i] * inv;
}

// ---------------- s1 partials = attn @ v over kv-splits ----------------
__global__ __launch_bounds__(256) void s1_partial_kernel(
    const float* __restrict__ attn, const float* __restrict__ v, float* __restrict__ part)
{
  __shared__ float a_s[NSEL][32];
  const int t    = threadIdx.x;
  const int dloc = t & 127;
  const int jg   = t >> 7;          // 0 or 1 (30 rows each)
  const int d0   = blockIdx.x * 128;
  const int b    = blockIdx.y;
  const int sp   = blockIdx.z;
  const int kvbase = sp * (KVN / S1SPLIT);   // 256 keys per split

  float acc[30];
#pragma unroll
  for (int i = 0; i < 30; ++i) acc[i] = 0.f;

  for (int kc = 0; kc < KVN / S1SPLIT; kc += 32) {
    __syncthreads();
    for (int x = t; x < NSEL * 32; x += 256) {
      int j = x >> 5, kk = x & 31;
      a_s[j][kk] = attn[((size_t)(b * NSEL + j)) * KVN + kvbase + kc + kk];
    }
    __syncthreads();
#pragma unroll 4
    for (int kk = 0; kk < 32; ++kk) {
      float vv = v[((size_t)b * KVN + kvbase + kc + kk) * DN + d0 + dloc];
#pragma unroll
      for (int jj = 0; jj < 30; ++jj)
        acc[jj] = fmaf(a_s[jg * 30 + jj][kk], vv, acc[jj]);
    }
  }
#pragma unroll
  for (int jj = 0; jj < 30; ++jj)
    part[((size_t)((sp * BATCH + b) * NSEL) + jg * 30 + jj) * DN + d0 + dloc] = acc[jj];
}

// ---------------- v mean (2-stage) ----------------
__global__ __launch_bounds__(256) void vmean_part_kernel(
    const float* __restrict__ v, float* __restrict__ vpart)
{
  const int t = threadIdx.x;
  const int c = blockIdx.x;   // 0..15
  const int b = blockIdx.y;
  const int kv0 = c * 128;
  for (int d = t; d < DN; d += 256) {
    float s = 0.f;
    for (int r = 0; r < 128; ++r) s += v[((size_t)b * KVN + kv0 + r) * DN + d];
    vpart[(size_t)(c * BATCH + b) * DN + d] = s;
  }
}

__global__ void vmean_combine_kernel(const float* __restrict__ vpart, float* __restrict__ vmean)
{
  int idx = blockIdx.x * 256 + threadIdx.x;   // 0..2047
  if (idx < BATCH * DN) {
    int b = idx / DN, d = idx % DN;
    float s = 0.f;
    for (int c = 0; c < 16; ++c) s += vpart[(size_t)(c * BATCH + b) * DN + d];
    vmean[idx] = s * (1.0f / (float)KVN);
  }
}

// ---------------- fill output with v-mean ----------------
__global__ __launch_bounds__(256) void fill_kernel(
    const float* __restrict__ vmean, float* __restrict__ out)
{
  size_t gid = (size_t)blockIdx.x * 256 + threadIdx.x;   // float4 index
  size_t e = gid * 4;
  int b = (int)(e >> 20);          // Q*D = 1<<20 per batch
  int d = (int)(e & (DN - 1));
  float4 mv = *reinterpret_cast<const float4*>(vmean + b * DN + d);
  *reinterpret_cast<float4*>(out + e) = mv;
}

// ---------------- combine s1 partials & scatter to selected rows ----------------
__global__ void scatter_kernel(const float* __restrict__ part,
                               const int* __restrict__ topidx, float* __restrict__ out)
{
  const int t = threadIdx.x;   // 128
  const int j = blockIdx.x;    // 0..59
  const int b = blockIdx.y;
  const int row = topidx[b * 64 + j];
  const int d = t * 4;
  float4 s = make_float4(0.f, 0.f, 0.f, 0.f);
  for (int sp = 0; sp < S1SPLIT; ++sp) {
    float4 p = *reinterpret_cast<const float4*>(
        part + ((size_t)((sp * BATCH + b) * NSEL) + j) * DN + d);
    s.x += p.x; s.y += p.y; s.z += p.z; s.w += p.w;
  }
  *reinterpret_cast<float4*>(out + ((size_t)b * QN + row) * DN + d) = s;
}

// ---------------- launcher ----------------
extern "C" void kernel_launch(void* const* d_in, const int* in_sizes, int n_in,
                              void* d_out, int out_size, void* d_ws, size_t ws_size,
                              hipStream_t stream) {
  const float* q    = (const float*)d_in[0];
  const float* k    = (const float*)d_in[1];
  const float* v    = (const float*)d_in[2];
  const int*   sidx = (const int*)d_in[3];
  float* out = (float*)d_out;
  char*  W   = (char*)d_ws;

  // region A [0, 32 MB): bf16 splits (dead after s_mfma_kernel)
  const size_t NEL = (size_t)BATCH * QN * DN;   // 4,194,304
  unsigned short* qh = (unsigned short*)W;
  unsigned short* ql = qh + NEL;
  unsigned short* kh = ql + NEL;
  unsigned short* kl = kh + NEL;

  // region B [32 MB, ~34.2 MB): live across phase boundary
  char* W2 = W + 4 * NEL * sizeof(unsigned short);
  float* cnt    = (float*)W2;                         // 32 KB
  float* Pmax   = (float*)(W2 + 32768);               // 1 MB
  float* Psum   = (float*)(W2 + 32768 + 1048576);     // 1 MB
  float* Mbuf   = (float*)(W2 + 32768 + 2097152);     // 32 KB
  int*   topidx = (int*)(W2 + 32768 + 2097152 + 32768); // 1 KB

  // post-phase-1 buffers aliased into region A (splits are dead by then)
  float* qbar  = (float*)W;                 // 512 KB
  float* attn  = (float*)(W + 524288);      // 1.875 MB
  float* part  = (float*)(W + 2490368);     // 3.75 MB
  float* vpart = (float*)(W + 6422528);     // 128 KB
  float* vmean = (float*)(W + 6553600);     // 8 KB

  split_kernel<<<dim3(4096), 256, 0, stream>>>(q, qh, ql);
  split_kernel<<<dim3(4096), 256, 0, stream>>>(k, kh, kl);
  count_kernel<<<dim3(BATCH), 256, 0, stream>>>(sidx, cnt);
  s_mfma_kernel<<<dim3(512), 256, 0, stream>>>(qh, ql, kh, kl, cnt, Pmax, Psum);
  combine_kernel<<<dim3(BATCH * QN / 256), 256, 0, stream>>>(Pmax, Psum, Mbuf);
  select_kernel<<<dim3(BATCH), 64, 0, stream>>>(Mbuf, topidx);
  gather_qbar_kernel<<<dim3(64, BATCH), 128, 0, stream>>>(q, topidx, qbar);
  scores_kernel<<<dim3(KVN / SBN, BATCH), 256, 0, stream>>>(qbar, k, attn);
  softmax_kernel<<<dim3(BATCH * NSEL), 256, 0, stream>>>(attn);
  s1_partial_kernel<<<dim3(4, BATCH, S1SPLIT), 256, 0, stream>>>(attn, v, part);
  vmean_part_kernel<<<dim3(16, BATCH), 256, 0, stream>>>(v, vpart);
  vmean_combine_kernel<<<dim3(8), 256, 0, stream>>>(vpart, vmean);
  fill_kernel<<<dim3(4096), 256, 0, stream>>>(vmean, out);
  scatter_kernel<<<dim3(NSEL, BATCH), 128, 0, stream>>>(part, topidx, out);
}

// Round 5
// 323.332 us; speedup vs baseline: 5.8290x; 1.2404x over previous
//
#include <hip/hip_runtime.h>
#include <math.h>

// Problem constants (B=4, Q=2048, KV=2048, D=512)
#define BATCH 4
#define QN    2048
#define KVN   2048
#define DN    512
#define U_TOT 15615          // int(Q * ln(KV))
#define NSEL  60             // int(8 * ln(Q))
#define NSLOT 32             // 16 j-tiles x 2 n-half waves
#define S1KS  32             // kv-splits for s1 = attn @ v (64 rows each)

typedef __attribute__((ext_vector_type(8))) short bf16x8;
typedef __attribute__((ext_vector_type(4))) float f32x4;

// ---------------- helpers ----------------
__device__ __forceinline__ unsigned short f2bf(float f) {
  unsigned u = __float_as_uint(f);
  unsigned r = (u + 0x7fffu + ((u >> 16) & 1u)) >> 16;   // RNE
  return (unsigned short)r;
}
__device__ __forceinline__ float bf2f(unsigned short h) {
  return __uint_as_float(((unsigned)h) << 16);
}
__device__ __forceinline__ void gld16(const void* g, void* l) {
  __builtin_amdgcn_global_load_lds(
      (const __attribute__((address_space(1))) unsigned int*)g,
      (__attribute__((address_space(3))) unsigned int*)l, 16, 0, 0);
}
__device__ __forceinline__ unsigned long long shfl_xor_u64(unsigned long long v, int o) {
  unsigned lo = (unsigned)v, hi = (unsigned)(v >> 32);
  lo = (unsigned)__shfl_xor((int)lo, o);
  hi = (unsigned)__shfl_xor((int)hi, o);
  return ((unsigned long long)hi << 32) | lo;
}

// ---------------- split fp32 -> bf16 hi/lo ----------------
__global__ __launch_bounds__(256) void split_kernel(
    const float* __restrict__ in, unsigned short* __restrict__ hi,
    unsigned short* __restrict__ lo)
{
  int i = blockIdx.x * 256 + threadIdx.x;   // float4 index; grid covers exactly n/4
  float4 f = reinterpret_cast<const float4*>(in)[i];
  ushort4 h, l;
  h.x = f2bf(f.x); l.x = f2bf(f.x - bf2f(h.x));
  h.y = f2bf(f.y); l.y = f2bf(f.y - bf2f(h.y));
  h.z = f2bf(f.z); l.z = f2bf(f.z - bf2f(h.z));
  h.w = f2bf(f.w); l.w = f2bf(f.w - bf2f(h.w));
  reinterpret_cast<ushort4*>(hi)[i] = h;
  reinterpret_cast<ushort4*>(lo)[i] = l;
}

// ---------------- counts histogram: cnt[b][j] = multiplicity of key j ----------------
__global__ __launch_bounds__(256) void count_kernel(
    const int* __restrict__ sidx, float* __restrict__ cnt)
{
  __shared__ int h[KVN];
  const int b = blockIdx.x, t = threadIdx.x;
  for (int i = t; i < KVN; i += 256) h[i] = 0;
  __syncthreads();
  for (int i = t; i < U_TOT; i += 256) atomicAdd(&h[sidx[b * U_TOT + i]], 1);
  __syncthreads();
  for (int i = t; i < KVN; i += 256) cnt[b * KVN + i] = (float)h[i];
}

// ---------------- Phase 1: dense S = q @ k^T with fused masked-max / weighted-sum ----
// 512 blocks; each: one 128-j tile x two 128-q tiles, K=512 in BK=32, 3 MFMA passes.
__global__ __launch_bounds__(256) void s_mfma_kernel(
    const unsigned short* __restrict__ qh, const unsigned short* __restrict__ ql,
    const unsigned short* __restrict__ kh, const unsigned short* __restrict__ kl,
    const float* __restrict__ cnt, float* __restrict__ Pmax, float* __restrict__ Psum)
{
  __shared__ unsigned short Ah[128 * 32];
  __shared__ unsigned short Al[128 * 32];
  __shared__ unsigned short Bh[128 * 32];
  __shared__ unsigned short Bl[128 * 32];
  __shared__ float cnt_s[128];

  const int t = threadIdx.x;
  const int w = t >> 6;          // wave 0..3
  const int L = t & 63;
  const int mbase = (w & 1) * 64;
  const int nbase = (w >> 1) * 64;
  const int lm = L & 15;
  const int lk = (L >> 4) * 8;

  // XCD swizzle: xcd = bid&7 -> batch = xcd>>1, j-half = xcd&1
  const int bid = blockIdx.x;
  const int xcd = bid & 7;
  const int idx = bid >> 3;      // 0..63
  const int b   = xcd >> 1;
  const int ji  = (xcd & 1) * 8 + (idx >> 3);   // 0..15
  const int qi0 = (idx & 7) * 2;                // q-tile pair
  const int j0  = ji * 128;

  if (t < 128) cnt_s[t] = cnt[b * KVN + j0 + t];

  const size_t koff0 = ((size_t)(b * KVN) + j0 + (t >> 2)) * DN + (size_t)((t & 3) * 8);
  const size_t koff1 = koff0 + (size_t)64 * DN;

  for (int qq = 0; qq < 2; ++qq) {
    const int q0 = (qi0 + qq) * 128;
    const size_t qoff0 = ((size_t)(b * QN) + q0 + (t >> 2)) * DN + (size_t)((t & 3) * 8);
    const size_t qoff1 = qoff0 + (size_t)64 * DN;

    f32x4 acc[4][4];   // [nf][mf]
#pragma unroll
    for (int nf = 0; nf < 4; ++nf)
#pragma unroll
      for (int mf = 0; mf < 4; ++mf) {
        acc[nf][mf][0] = 0.f; acc[nf][mf][1] = 0.f;
        acc[nf][mf][2] = 0.f; acc[nf][mf][3] = 0.f;
      }

    for (int d0 = 0; d0 < DN; d0 += 32) {
      __syncthreads();   // LDS reads from previous step done
      gld16(qh + qoff0 + d0, &Ah[t * 8]);
      gld16(qh + qoff1 + d0, &Ah[(t + 256) * 8]);
      gld16(ql + qoff0 + d0, &Al[t * 8]);
      gld16(ql + qoff1 + d0, &Al[(t + 256) * 8]);
      gld16(kh + koff0 + d0, &Bh[t * 8]);
      gld16(kh + koff1 + d0, &Bh[(t + 256) * 8]);
      gld16(kl + koff0 + d0, &Bl[t * 8]);
      gld16(kl + koff1 + d0, &Bl[(t + 256) * 8]);
      __syncthreads();

      bf16x8 ah[4], al[4];
#pragma unroll
      for (int mf = 0; mf < 4; ++mf) {
        const int m = mbase + mf * 16 + lm;
        ah[mf] = *reinterpret_cast<const bf16x8*>(&Ah[m * 32 + lk]);
        al[mf] = *reinterpret_cast<const bf16x8*>(&Al[m * 32 + lk]);
      }
#pragma unroll
      for (int nf = 0; nf < 4; ++nf) {
        const int n = nbase + nf * 16 + lm;
        bf16x8 bh = *reinterpret_cast<const bf16x8*>(&Bh[n * 32 + lk]);
        bf16x8 bl = *reinterpret_cast<const bf16x8*>(&Bl[n * 32 + lk]);
#pragma unroll
        for (int mf = 0; mf < 4; ++mf) {
          acc[nf][mf] = __builtin_amdgcn_mfma_f32_16x16x32_bf16(ah[mf], bh, acc[nf][mf], 0, 0, 0);
          acc[nf][mf] = __builtin_amdgcn_mfma_f32_16x16x32_bf16(ah[mf], bl, acc[nf][mf], 0, 0, 0);
          acc[nf][mf] = __builtin_amdgcn_mfma_f32_16x16x32_bf16(al[mf], bh, acc[nf][mf], 0, 0, 0);
        }
      }
    }

    // fused epilogue: masked max + count-weighted sum over this j-tile
    // C/D map: j(col) = lane&15, q(row) = (lane>>4)*4 + reg  [m89-verified]
    float mx[4][4], wsm[4][4];
#pragma unroll
    for (int mf = 0; mf < 4; ++mf)
#pragma unroll
      for (int r = 0; r < 4; ++r) { mx[mf][r] = -INFINITY; wsm[mf][r] = 0.f; }

#pragma unroll
    for (int nf = 0; nf < 4; ++nf) {
      const float c = cnt_s[nbase + nf * 16 + lm];
      const bool has = (c > 0.f);
#pragma unroll
      for (int mf = 0; mf < 4; ++mf)
#pragma unroll
        for (int r = 0; r < 4; ++r) {
          const float v = acc[nf][mf][r];
          if (has) mx[mf][r] = fmaxf(mx[mf][r], v);
          wsm[mf][r] = fmaf(c, v, wsm[mf][r]);
        }
    }

    const size_t spi = (size_t)((ji * 2 + (w >> 1)) * BATCH + b);
#pragma unroll
    for (int mf = 0; mf < 4; ++mf)
#pragma unroll
      for (int r = 0; r < 4; ++r) {
        float m = mx[mf][r], s = wsm[mf][r];
#pragma unroll
        for (int o = 1; o < 16; o <<= 1) {
          m = fmaxf(m, __shfl_xor(m, o));
          s += __shfl_xor(s, o);
        }
        if (lm == 0) {
          const int qrow = q0 + mbase + mf * 16 + (L >> 4) * 4 + r;
          Pmax[spi * QN + qrow] = m;
          Psum[spi * QN + qrow] = s;
        }
      }
  }
}

// ---------------- Phase 2a: wide combine of the 32 partial slots -> M[b][q] --------
__global__ __launch_bounds__(256) void combine_kernel(
    const float* __restrict__ Pmax, const float* __restrict__ Psum, float* __restrict__ M)
{
  const int g = blockIdx.x * 256 + threadIdx.x;   // 0 .. BATCH*QN-1
  const int b = g >> 11;                          // QN = 2048
  const int qq = g & (QN - 1);
  float m = -INFINITY, s = 0.f;
#pragma unroll 4
  for (int p = 0; p < NSLOT; ++p) {
    m = fmaxf(m, Pmax[((size_t)(p * BATCH + b)) * QN + qq]);
    s += Psum[((size_t)(p * BATCH + b)) * QN + qq];
  }
  M[g] = m - s * (1.0f / (float)U_TOT);
}

// ---------------- Phase 2b: iterative top-60 (jax tie-break), 1 wave/batch --------
__global__ __launch_bounds__(64) void select_kernel(
    const float* __restrict__ M, int* __restrict__ topidx)
{
  const int b = blockIdx.x;
  const int L = threadIdx.x;
  unsigned long long key[32];
#pragma unroll
  for (int s = 0; s < 32; ++s) {
    const int qq = s * 64 + L;
    unsigned u = __float_as_uint(M[b * QN + qq]);
    u = (u & 0x80000000u) ? ~u : (u | 0x80000000u);   // order-preserving map
    key[s] = ((unsigned long long)u << 32) | (unsigned)(QN - qq);
  }
  for (int it = 0; it < NSEL; ++it) {
    unsigned long long best = key[0];
#pragma unroll
    for (int s = 1; s < 32; ++s) best = (key[s] > best) ? key[s] : best;
    for (int o = 1; o < 64; o <<= 1) {
      unsigned long long oth = shfl_xor_u64(best, o);
      best = (oth > best) ? oth : best;
    }
    const int qsel = QN - (int)(best & 0xFFFFFFFFull);
    if (L == 0) topidx[b * 64 + it] = qsel;
    const int slot = qsel >> 6;
    const bool own = ((qsel & 63) == L);
#pragma unroll
    for (int s = 0; s < 32; ++s)
      if (own && s == slot) key[s] = 0ull;
  }
}

// ---------------- gather q_bar (padded to 64 rows) ----------------
__global__ void gather_qbar_kernel(const float* __restrict__ q,
                                   const int* __restrict__ topidx, float* __restrict__ qbar)
{
  const int j = blockIdx.x;   // 0..63
  const int b = blockIdx.y;
  const int t = threadIdx.x;  // 128
  float4 val = make_float4(0.f, 0.f, 0.f, 0.f);
  if (j < NSEL) {
    int row = topidx[b * 64 + j];
    val = *reinterpret_cast<const float4*>(q + ((size_t)b * QN + row) * DN + t * 4);
  }
  *reinterpret_cast<float4*>(qbar + ((size_t)(b * 64 + j)) * DN + t * 4) = val;
}

// ---------------- scores = q_bar @ k^T (raw, unscaled, fp32) ----------------
#define SBM 64
#define SBN 64
#define SBK 32
__global__ __launch_bounds__(256) void scores_kernel(
    const float* __restrict__ qbar, const float* __restrict__ k, float* __restrict__ attn)
{
  __shared__ float a_s[SBK][SBM + 4];
  __shared__ float b_s[SBK][SBN + 4];
  const int t  = threadIdx.x;
  const int tx = t & 15, ty = t >> 4;
  const int kv0 = blockIdx.x * SBN;
  const int b   = blockIdx.y;
  const float* qb = qbar + (size_t)b * 64 * DN;
  const float* kb = k + (size_t)b * KVN * DN;

  float acc[4][4];
#pragma unroll
  for (int i = 0; i < 4; ++i)
#pragma unroll
    for (int j = 0; j < 4; ++j) acc[i][j] = 0.f;

  const int c4 = (t & 7) * 4;
  const int r0 = t >> 3;   // 0..31

  for (int d0 = 0; d0 < DN; d0 += SBK) {
#pragma unroll
    for (int rr = 0; rr < 2; ++rr) {
      int row = r0 + rr * 32;
      float4 av = *reinterpret_cast<const float4*>(qb + (size_t)row * DN + d0 + c4);
      a_s[c4 + 0][row] = av.x; a_s[c4 + 1][row] = av.y;
      a_s[c4 + 2][row] = av.z; a_s[c4 + 3][row] = av.w;
      float4 bv = *reinterpret_cast<const float4*>(kb + (size_t)(kv0 + row) * DN + d0 + c4);
      b_s[c4 + 0][row] = bv.x; b_s[c4 + 1][row] = bv.y;
      b_s[c4 + 2][row] = bv.z; b_s[c4 + 3][row] = bv.w;
    }
    __syncthreads();
#pragma unroll
    for (int kk = 0; kk < SBK; ++kk) {
      float4 av = *reinterpret_cast<const float4*>(&a_s[kk][ty * 4]);
      float4 bv = *reinterpret_cast<const float4*>(&b_s[kk][tx * 4]);
      float af[4] = {av.x, av.y, av.z, av.w};
      float bf[4] = {bv.x, bv.y, bv.z, bv.w};
#pragma unroll
      for (int i = 0; i < 4; ++i)
#pragma unroll
        for (int j = 0; j < 4; ++j)
          acc[i][j] = fmaf(af[i], bf[j], acc[i][j]);
    }
    __syncthreads();
  }

#pragma unroll
  for (int i = 0; i < 4; ++i) {
    int j = ty * 4 + i;
    if (j < NSEL) {
      float4 o = make_float4(acc[i][0], acc[i][1], acc[i][2], acc[i][3]);
      *reinterpret_cast<float4*>(attn + ((size_t)(b * NSEL + j)) * KVN + kv0 + tx * 4) = o;
    }
  }
}

// ---------------- softmax over 2048 keys per selected row ----------------
__global__ __launch_bounds__(256) void softmax_kernel(float* __restrict__ attn)
{
  __shared__ float buf[KVN];
  __shared__ float red[256];
  const int t = threadIdx.x;
  float* row = attn + (size_t)blockIdx.x * KVN;

  float m = -INFINITY;
  for (int i = t; i < KVN; i += 256) { float v = row[i]; buf[i] = v; m = fmaxf(m, v); }
  red[t] = m;
  __syncthreads();
  for (int off = 128; off > 0; off >>= 1) {
    if (t < off) red[t] = fmaxf(red[t], red[t + off]);
    __syncthreads();
  }
  m = red[0];
  __syncthreads();

  const float sc = 0.022097086912079608f;   // 1/sqrt(2048)
  float s = 0.f;
  for (int i = t; i < KVN; i += 256) { float e = __expf((buf[i] - m) * sc); buf[i] = e; s += e; }
  red[t] = s;
  __syncthreads();
  for (int off = 128; off > 0; off >>= 1) {
    if (t < off) red[t] += red[t + off];
    __syncthreads();
  }
  float inv = 1.f / red[0];
  for (int i = t; i < KVN; i += 256) row[i] = buf[i] * inv;
}

// ---------------- s1 partials = attn @ v, float4 per lane, 32 kv-splits ----------
// grid (2 d-halves, BATCH, S1KS); block 256 = 64 dv4 x 4 j-groups (15 j each).
__global__ __launch_bounds__(256) void s1_partial_kernel(
    const float* __restrict__ attn, const float* __restrict__ v, float* __restrict__ part)
{
  __shared__ float a_s[64][61];     // [kv-local][j], padded: stride 61 is odd
  const int t    = threadIdx.x;
  const int dv4  = t & 63;          // float4 column within the d-half
  const int jg   = t >> 6;          // 0..3 -> j in [jg*15, jg*15+15)
  const int dh   = blockIdx.x;      // d-half: 0 or 1
  const int b    = blockIdx.y;
  const int ks   = blockIdx.z;      // kv split
  const int kv0  = ks * 64;
  const int dbase = dh * 256 + dv4 * 4;

  // stage attn tile: 60 j x 64 kv, coalesced along kv
  for (int x = t; x < NSEL * 64; x += 256) {
    const int j = x >> 6, kk = x & 63;
    a_s[kk][j] = attn[((size_t)(b * NSEL + j)) * KVN + kv0 + kk];
  }
  __syncthreads();

  f32x4 acc[15];
#pragma unroll
  for (int i = 0; i < 15; ++i) { acc[i][0] = 0.f; acc[i][1] = 0.f; acc[i][2] = 0.f; acc[i][3] = 0.f; }

  const float* vb = v + ((size_t)b * KVN + kv0) * DN + dbase;
#pragma unroll 8
  for (int kk = 0; kk < 64; ++kk) {
    const f32x4 vv = *reinterpret_cast<const f32x4*>(vb + (size_t)kk * DN);
#pragma unroll
    for (int jj = 0; jj < 15; ++jj) {
      const float a = a_s[kk][jg * 15 + jj];   // wave-uniform broadcast
      acc[jj][0] = fmaf(a, vv[0], acc[jj][0]);
      acc[jj][1] = fmaf(a, vv[1], acc[jj][1]);
      acc[jj][2] = fmaf(a, vv[2], acc[jj][2]);
      acc[jj][3] = fmaf(a, vv[3], acc[jj][3]);
    }
  }

#pragma unroll
  for (int jj = 0; jj < 15; ++jj) {
    const int j = jg * 15 + jj;
    *reinterpret_cast<f32x4*>(
        part + ((size_t)((ks * BATCH + b) * NSEL) + j) * DN + dbase) = acc[jj];
  }
}

// ---------------- v mean (2-stage) ----------------
__global__ __launch_bounds__(256) void vmean_part_kernel(
    const float* __restrict__ v, float* __restrict__ vpart)
{
  const int t = threadIdx.x;
  const int c = blockIdx.x;   // 0..15
  const int b = blockIdx.y;
  const int kv0 = c * 128;
  for (int d = t; d < DN; d += 256) {
    float s = 0.f;
    for (int r = 0; r < 128; ++r) s += v[((size_t)b * KVN + kv0 + r) * DN + d];
    vpart[(size_t)(c * BATCH + b) * DN + d] = s;
  }
}

__global__ void vmean_combine_kernel(const float* __restrict__ vpart, float* __restrict__ vmean)
{
  int idx = blockIdx.x * 256 + threadIdx.x;   // 0..2047
  if (idx < BATCH * DN) {
    int b = idx / DN, d = idx % DN;
    float s = 0.f;
    for (int c = 0; c < 16; ++c) s += vpart[(size_t)(c * BATCH + b) * DN + d];
    vmean[idx] = s * (1.0f / (float)KVN);
  }
}

// ---------------- fill output with v-mean ----------------
__global__ __launch_bounds__(256) void fill_kernel(
    const float* __restrict__ vmean, float* __restrict__ out)
{
  size_t gid = (size_t)blockIdx.x * 256 + threadIdx.x;   // float4 index
  size_t e = gid * 4;
  int b = (int)(e >> 20);          // Q*D = 1<<20 per batch
  int d = (int)(e & (DN - 1));
  float4 mv = *reinterpret_cast<const float4*>(vmean + b * DN + d);
  *reinterpret_cast<float4*>(out + e) = mv;
}

// ---------------- combine s1 partials & scatter to selected rows ----------------
__global__ void scatter_kernel(const float* __restrict__ part,
                               const int* __restrict__ topidx, float* __restrict__ out)
{
  const int t = threadIdx.x;   // 128
  const int j = blockIdx.x;    // 0..59
  const int b = blockIdx.y;
  const int row = topidx[b * 64 + j];
  const int d = t * 4;
  float4 s = make_float4(0.f, 0.f, 0.f, 0.f);
  for (int sp = 0; sp < S1KS; ++sp) {
    float4 p = *reinterpret_cast<const float4*>(
        part + ((size_t)((sp * BATCH + b) * NSEL) + j) * DN + d);
    s.x += p.x; s.y += p.y; s.z += p.z; s.w += p.w;
  }
  *reinterpret_cast<float4*>(out + ((size_t)b * QN + row) * DN + d) = s;
}

// ---------------- launcher ----------------
extern "C" void kernel_launch(void* const* d_in, const int* in_sizes, int n_in,
                              void* d_out, int out_size, void* d_ws, size_t ws_size,
                              hipStream_t stream) {
  const float* q    = (const float*)d_in[0];
  const float* k    = (const float*)d_in[1];
  const float* v    = (const float*)d_in[2];
  const int*   sidx = (const int*)d_in[3];
  float* out = (float*)d_out;
  char*  W   = (char*)d_ws;

  // region A [0, 32 MB): bf16 splits (dead after s_mfma_kernel)
  const size_t NEL = (size_t)BATCH * QN * DN;   // 4,194,304
  unsigned short* qh = (unsigned short*)W;
  unsigned short* ql = qh + NEL;
  unsigned short* kh = ql + NEL;
  unsigned short* kl = kh + NEL;

  // region B [32 MB, ~34.2 MB): live across phase boundary
  char* W2 = W + 4 * NEL * sizeof(unsigned short);
  float* cnt    = (float*)W2;                         // 32 KB
  float* Pmax   = (float*)(W2 + 32768);               // 1 MB
  float* Psum   = (float*)(W2 + 32768 + 1048576);     // 1 MB
  float* Mbuf   = (float*)(W2 + 32768 + 2097152);     // 32 KB
  int*   topidx = (int*)(W2 + 32768 + 2097152 + 32768); // 1 KB

  // post-phase-1 buffers aliased into region A (splits are dead by then)
  float* qbar  = (float*)W;                  // 512 KB
  float* attn  = (float*)(W + 524288);       // 1.875 MB
  float* part  = (float*)(W + 2490368);      // 32*4*60*512*4 = 15.0 MB
  float* vpart = (float*)(W + 18219008);     // 128 KB
  float* vmean = (float*)(W + 18350080);     // 8 KB -> ends 18.4 MB < 32 MB

  split_kernel<<<dim3(4096), 256, 0, stream>>>(q, qh, ql);
  split_kernel<<<dim3(4096), 256, 0, stream>>>(k, kh, kl);
  count_kernel<<<dim3(BATCH), 256, 0, stream>>>(sidx, cnt);
  s_mfma_kernel<<<dim3(512), 256, 0, stream>>>(qh, ql, kh, kl, cnt, Pmax, Psum);
  combine_kernel<<<dim3(BATCH * QN / 256), 256, 0, stream>>>(Pmax, Psum, Mbuf);
  select_kernel<<<dim3(BATCH), 64, 0, stream>>>(Mbuf, topidx);
  gather_qbar_kernel<<<dim3(64, BATCH), 128, 0, stream>>>(q, topidx, qbar);
  scores_kernel<<<dim3(KVN / SBN, BATCH), 256, 0, stream>>>(qbar, k, attn);
  softmax_kernel<<<dim3(BATCH * NSEL), 256, 0, stream>>>(attn);
  s1_partial_kernel<<<dim3(2, BATCH, S1KS), 256, 0, stream>>>(attn, v, part);
  vmean_part_kernel<<<dim3(16, BATCH), 256, 0, stream>>>(v, vpart);
  vmean_combine_kernel<<<dim3(8), 256, 0, stream>>>(vpart, vmean);
  fill_kernel<<<dim3(4096), 256, 0, stream>>>(vmean, out);
  scatter_kernel<<<dim3(NSEL, BATCH), 128, 0, stream>>>(part, topidx, out);
}

// Round 6
// 259.142 us; speedup vs baseline: 7.2728x; 1.2477x over previous
//
#include <hip/hip_runtime.h>
#include <math.h>

// Problem constants (B=4, Q=2048, KV=2048, D=512)
#define BATCH 4
#define QN    2048
#define KVN   2048
#define DN    512
#define U_TOT 15615          // int(Q * ln(KV))
#define NSEL  60             // int(8 * ln(Q))
#define NSLOT 32             // 16 j-tiles x 2 n-half waves
#define S1KS  32             // kv-splits for s1 = attn @ v (64 rows each)

typedef __attribute__((ext_vector_type(8))) short bf16x8;
typedef __attribute__((ext_vector_type(4))) float f32x4;

// ---------------- helpers ----------------
__device__ __forceinline__ unsigned short f2bf(float f) {
  unsigned u = __float_as_uint(f);
  unsigned r = (u + 0x7fffu + ((u >> 16) & 1u)) >> 16;   // RNE
  return (unsigned short)r;
}
__device__ __forceinline__ float bf2f(unsigned short h) {
  return __uint_as_float(((unsigned)h) << 16);
}
__device__ __forceinline__ void gld16(const void* g, void* l) {
  __builtin_amdgcn_global_load_lds(
      (const __attribute__((address_space(1))) unsigned int*)g,
      (__attribute__((address_space(3))) unsigned int*)l, 16, 0, 0);
}

// ---------------- split fp32 -> bf16 hi/lo (q and k in one dispatch) ----------------
__global__ __launch_bounds__(256) void split_kernel(
    const float* __restrict__ q, const float* __restrict__ k,
    unsigned short* __restrict__ qhi, unsigned short* __restrict__ qlo,
    unsigned short* __restrict__ khi, unsigned short* __restrict__ klo)
{
  const int half = blockIdx.x >> 12;                       // 0 = q, 1 = k (4096 blocks each)
  const int i = (blockIdx.x & 4095) * 256 + threadIdx.x;   // float4 index
  const float* in = half ? k : q;
  unsigned short* hi = half ? khi : qhi;
  unsigned short* lo = half ? klo : qlo;
  float4 f = reinterpret_cast<const float4*>(in)[i];
  ushort4 h, l;
  h.x = f2bf(f.x); l.x = f2bf(f.x - bf2f(h.x));
  h.y = f2bf(f.y); l.y = f2bf(f.y - bf2f(h.y));
  h.z = f2bf(f.z); l.z = f2bf(f.z - bf2f(h.z));
  h.w = f2bf(f.w); l.w = f2bf(f.w - bf2f(h.w));
  reinterpret_cast<ushort4*>(hi)[i] = h;
  reinterpret_cast<ushort4*>(lo)[i] = l;
}

// ---------------- counts histogram: cnt[b][j] = multiplicity of key j ----------------
__global__ __launch_bounds__(256) void count_kernel(
    const int* __restrict__ sidx, float* __restrict__ cnt)
{
  __shared__ int h[KVN];
  const int b = blockIdx.x, t = threadIdx.x;
  for (int i = t; i < KVN; i += 256) h[i] = 0;
  __syncthreads();
  for (int i = t; i < U_TOT; i += 256) atomicAdd(&h[sidx[b * U_TOT + i]], 1);
  __syncthreads();
  for (int i = t; i < KVN; i += 256) cnt[b * KVN + i] = (float)h[i];
}

// ---------------- Phase 1: dense S = q @ k^T with fused masked-max / weighted-sum ----
// 512 blocks; each: one 128-j tile x two 128-q tiles, K=512 in BK=32, 3 MFMA passes.
__global__ __launch_bounds__(256) void s_mfma_kernel(
    const unsigned short* __restrict__ qh, const unsigned short* __restrict__ ql,
    const unsigned short* __restrict__ kh, const unsigned short* __restrict__ kl,
    const float* __restrict__ cnt, float* __restrict__ Pmax, float* __restrict__ Psum)
{
  __shared__ unsigned short Ah[128 * 32];
  __shared__ unsigned short Al[128 * 32];
  __shared__ unsigned short Bh[128 * 32];
  __shared__ unsigned short Bl[128 * 32];
  __shared__ float cnt_s[128];

  const int t = threadIdx.x;
  const int w = t >> 6;          // wave 0..3
  const int L = t & 63;
  const int mbase = (w & 1) * 64;
  const int nbase = (w >> 1) * 64;
  const int lm = L & 15;
  const int lk = (L >> 4) * 8;

  // XCD swizzle: xcd = bid&7 -> batch = xcd>>1, j-half = xcd&1
  const int bid = blockIdx.x;
  const int xcd = bid & 7;
  const int idx = bid >> 3;      // 0..63
  const int b   = xcd >> 1;
  const int ji  = (xcd & 1) * 8 + (idx >> 3);   // 0..15
  const int qi0 = (idx & 7) * 2;                // q-tile pair
  const int j0  = ji * 128;

  if (t < 128) cnt_s[t] = cnt[b * KVN + j0 + t];

  const size_t koff0 = ((size_t)(b * KVN) + j0 + (t >> 2)) * DN + (size_t)((t & 3) * 8);
  const size_t koff1 = koff0 + (size_t)64 * DN;

  for (int qq = 0; qq < 2; ++qq) {
    const int q0 = (qi0 + qq) * 128;
    const size_t qoff0 = ((size_t)(b * QN) + q0 + (t >> 2)) * DN + (size_t)((t & 3) * 8);
    const size_t qoff1 = qoff0 + (size_t)64 * DN;

    f32x4 acc[4][4];   // [nf][mf]
#pragma unroll
    for (int nf = 0; nf < 4; ++nf)
#pragma unroll
      for (int mf = 0; mf < 4; ++mf) {
        acc[nf][mf][0] = 0.f; acc[nf][mf][1] = 0.f;
        acc[nf][mf][2] = 0.f; acc[nf][mf][3] = 0.f;
      }

    for (int d0 = 0; d0 < DN; d0 += 32) {
      __syncthreads();   // LDS reads from previous step done
      gld16(qh + qoff0 + d0, &Ah[t * 8]);
      gld16(qh + qoff1 + d0, &Ah[(t + 256) * 8]);
      gld16(ql + qoff0 + d0, &Al[t * 8]);
      gld16(ql + qoff1 + d0, &Al[(t + 256) * 8]);
      gld16(kh + koff0 + d0, &Bh[t * 8]);
      gld16(kh + koff1 + d0, &Bh[(t + 256) * 8]);
      gld16(kl + koff0 + d0, &Bl[t * 8]);
      gld16(kl + koff1 + d0, &Bl[(t + 256) * 8]);
      __syncthreads();

      bf16x8 ah[4], al[4];
#pragma unroll
      for (int mf = 0; mf < 4; ++mf) {
        const int m = mbase + mf * 16 + lm;
        ah[mf] = *reinterpret_cast<const bf16x8*>(&Ah[m * 32 + lk]);
        al[mf] = *reinterpret_cast<const bf16x8*>(&Al[m * 32 + lk]);
      }
#pragma unroll
      for (int nf = 0; nf < 4; ++nf) {
        const int n = nbase + nf * 16 + lm;
        bf16x8 bh = *reinterpret_cast<const bf16x8*>(&Bh[n * 32 + lk]);
        bf16x8 bl = *reinterpret_cast<const bf16x8*>(&Bl[n * 32 + lk]);
#pragma unroll
        for (int mf = 0; mf < 4; ++mf) {
          acc[nf][mf] = __builtin_amdgcn_mfma_f32_16x16x32_bf16(ah[mf], bh, acc[nf][mf], 0, 0, 0);
          acc[nf][mf] = __builtin_amdgcn_mfma_f32_16x16x32_bf16(ah[mf], bl, acc[nf][mf], 0, 0, 0);
          acc[nf][mf] = __builtin_amdgcn_mfma_f32_16x16x32_bf16(al[mf], bh, acc[nf][mf], 0, 0, 0);
        }
      }
    }

    // fused epilogue: masked max + count-weighted sum over this j-tile
    // C/D map: j(col) = lane&15, q(row) = (lane>>4)*4 + reg  [m89-verified]
    float mx[4][4], wsm[4][4];
#pragma unroll
    for (int mf = 0; mf < 4; ++mf)
#pragma unroll
      for (int r = 0; r < 4; ++r) { mx[mf][r] = -INFINITY; wsm[mf][r] = 0.f; }

#pragma unroll
    for (int nf = 0; nf < 4; ++nf) {
      const float c = cnt_s[nbase + nf * 16 + lm];
      const bool has = (c > 0.f);
#pragma unroll
      for (int mf = 0; mf < 4; ++mf)
#pragma unroll
        for (int r = 0; r < 4; ++r) {
          const float v = acc[nf][mf][r];
          if (has) mx[mf][r] = fmaxf(mx[mf][r], v);
          wsm[mf][r] = fmaf(c, v, wsm[mf][r]);
        }
    }

    const size_t spi = (size_t)((ji * 2 + (w >> 1)) * BATCH + b);
#pragma unroll
    for (int mf = 0; mf < 4; ++mf)
#pragma unroll
      for (int r = 0; r < 4; ++r) {
        float m = mx[mf][r], s = wsm[mf][r];
#pragma unroll
        for (int o = 1; o < 16; o <<= 1) {
          m = fmaxf(m, __shfl_xor(m, o));
          s += __shfl_xor(s, o);
        }
        if (lm == 0) {
          const int qrow = q0 + mbase + mf * 16 + (L >> 4) * 4 + r;
          Pmax[spi * QN + qrow] = m;
          Psum[spi * QN + qrow] = s;
        }
      }
  }
}

// ---------------- Phase 2a: wide combine of the 32 partial slots -> M[b][q] --------
__global__ __launch_bounds__(256) void combine_kernel(
    const float* __restrict__ Pmax, const float* __restrict__ Psum, float* __restrict__ M)
{
  const int g = blockIdx.x * 256 + threadIdx.x;   // 0 .. BATCH*QN-1
  const int b = g >> 11;                          // QN = 2048
  const int qq = g & (QN - 1);
  float m = -INFINITY, s = 0.f;
#pragma unroll 4
  for (int p = 0; p < NSLOT; ++p) {
    m = fmaxf(m, Pmax[((size_t)(p * BATCH + b)) * QN + qq]);
    s += Psum[((size_t)(p * BATCH + b)) * QN + qq];
  }
  M[g] = m - s * (1.0f / (float)U_TOT);
}

// ---------------- Phase 2b: top-60 SET via MSB-first radix rank-select -----------
// Order of topidx is irrelevant (s1 rows follow the same permutation), so we find
// the 60th-largest packed key T and emit all keys >= T. Keys are distinct (index
// in low bits) and encode jax tie-breaking (value desc, then lower q first).
__global__ __launch_bounds__(256) void select_kernel(
    const float* __restrict__ M, int* __restrict__ topidx)
{
  const int b = blockIdx.x;
  const int t = threadIdx.x;
  unsigned long long key[8];
#pragma unroll
  for (int s = 0; s < 8; ++s) {
    const int qq = s * 256 + t;
    unsigned u = __float_as_uint(M[b * QN + qq]);
    u = (u & 0x80000000u) ? ~u : (u | 0x80000000u);   // order-preserving map
    key[s] = ((unsigned long long)u << 32) | (unsigned)(QN - qq);
  }

  __shared__ unsigned hist[256];
  __shared__ unsigned long long pref_s;
  __shared__ unsigned rank_s;
  __shared__ unsigned cnt_s;
  if (t == 0) { pref_s = 0ull; rank_s = NSEL; cnt_s = 0u; }
  __syncthreads();

  for (int level = 7; level >= 0; --level) {
    const int shift = level * 8;
    hist[t] = 0;
    __syncthreads();
    const unsigned long long pref = pref_s;
    const unsigned rank = rank_s;
#pragma unroll
    for (int s = 0; s < 8; ++s) {
      const bool match = (level == 7) || ((key[s] >> (shift + 8)) == pref);
      if (match) atomicAdd(&hist[(unsigned)((key[s] >> shift) & 255u)], 1u);
    }
    __syncthreads();
    if (t < 64) {   // wave 0: suffix-scan 256 buckets, 4 per lane
      const unsigned h0 = hist[4 * t], h1 = hist[4 * t + 1];
      const unsigned h2 = hist[4 * t + 2], h3 = hist[4 * t + 3];
      const unsigned loc = h0 + h1 + h2 + h3;
      unsigned run = loc;   // -> sum over lanes >= t
#pragma unroll
      for (int o = 1; o < 64; o <<= 1) {
        const unsigned oth = (unsigned)__shfl_down((int)run, o);
        if (t + o < 64) run += oth;
      }
      const unsigned suf = run - loc;       // cumGT past this lane's buckets
      const unsigned c3 = suf, c2 = c3 + h3, c1 = c2 + h2, c0 = c1 + h1;
      int hit = -1; unsigned cgt = 0;
      if      (c3 < rank && rank <= c3 + h3) { hit = 4 * t + 3; cgt = c3; }
      else if (c2 < rank && rank <= c2 + h2) { hit = 4 * t + 2; cgt = c2; }
      else if (c1 < rank && rank <= c1 + h1) { hit = 4 * t + 1; cgt = c1; }
      else if (c0 < rank && rank <= c0 + h0) { hit = 4 * t + 0; cgt = c0; }
      if (hit >= 0) {   // exactly one lane
        pref_s = ((level == 7) ? 0ull : (pref_s << 8)) | (unsigned long long)(unsigned)hit;
        rank_s = rank - cgt;
      }
    }
    __syncthreads();
  }

  const unsigned long long T = pref_s;   // 60th-largest key
#pragma unroll
  for (int s = 0; s < 8; ++s) {
    if (key[s] >= T) {
      const unsigned pos = atomicAdd(&cnt_s, 1u);
      topidx[b * 64 + pos] = QN - (int)(key[s] & 0xFFFFFFFFull);
    }
  }
}

// ---------------- gather q_bar (padded to 64 rows) ----------------
__global__ void gather_qbar_kernel(const float* __restrict__ q,
                                   const int* __restrict__ topidx, float* __restrict__ qbar)
{
  const int j = blockIdx.x;   // 0..63
  const int b = blockIdx.y;
  const int t = threadIdx.x;  // 128
  float4 val = make_float4(0.f, 0.f, 0.f, 0.f);
  if (j < NSEL) {
    int row = topidx[b * 64 + j];
    val = *reinterpret_cast<const float4*>(q + ((size_t)b * QN + row) * DN + t * 4);
  }
  *reinterpret_cast<float4*>(qbar + ((size_t)(b * 64 + j)) * DN + t * 4) = val;
}

// ---------------- scores = q_bar @ k^T (raw, unscaled, fp32) ----------------
#define SBM 64
#define SBN 64
#define SBK 32
__global__ __launch_bounds__(256) void scores_kernel(
    const float* __restrict__ qbar, const float* __restrict__ k, float* __restrict__ attn)
{
  __shared__ float a_s[SBK][SBM + 4];
  __shared__ float b_s[SBK][SBN + 4];
  const int t  = threadIdx.x;
  const int tx = t & 15, ty = t >> 4;
  const int kv0 = blockIdx.x * SBN;
  const int b   = blockIdx.y;
  const float* qb = qbar + (size_t)b * 64 * DN;
  const float* kb = k + (size_t)b * KVN * DN;

  float acc[4][4];
#pragma unroll
  for (int i = 0; i < 4; ++i)
#pragma unroll
    for (int j = 0; j < 4; ++j) acc[i][j] = 0.f;

  const int c4 = (t & 7) * 4;
  const int r0 = t >> 3;   // 0..31

  for (int d0 = 0; d0 < DN; d0 += SBK) {
#pragma unroll
    for (int rr = 0; rr < 2; ++rr) {
      int row = r0 + rr * 32;
      float4 av = *reinterpret_cast<const float4*>(qb + (size_t)row * DN + d0 + c4);
      a_s[c4 + 0][row] = av.x; a_s[c4 + 1][row] = av.y;
      a_s[c4 + 2][row] = av.z; a_s[c4 + 3][row] = av.w;
      float4 bv = *reinterpret_cast<const float4*>(kb + (size_t)(kv0 + row) * DN + d0 + c4);
      b_s[c4 + 0][row] = bv.x; b_s[c4 + 1][row] = bv.y;
      b_s[c4 + 2][row] = bv.z; b_s[c4 + 3][row] = bv.w;
    }
    __syncthreads();
#pragma unroll
    for (int kk = 0; kk < SBK; ++kk) {
      float4 av = *reinterpret_cast<const float4*>(&a_s[kk][ty * 4]);
      float4 bv = *reinterpret_cast<const float4*>(&b_s[kk][tx * 4]);
      float af[4] = {av.x, av.y, av.z, av.w};
      float bf[4] = {bv.x, bv.y, bv.z, bv.w};
#pragma unroll
      for (int i = 0; i < 4; ++i)
#pragma unroll
        for (int j = 0; j < 4; ++j)
          acc[i][j] = fmaf(af[i], bf[j], acc[i][j]);
    }
    __syncthreads();
  }

#pragma unroll
  for (int i = 0; i < 4; ++i) {
    int j = ty * 4 + i;
    if (j < NSEL) {
      float4 o = make_float4(acc[i][0], acc[i][1], acc[i][2], acc[i][3]);
      *reinterpret_cast<float4*>(attn + ((size_t)(b * NSEL + j)) * KVN + kv0 + tx * 4) = o;
    }
  }
}

// ---------------- softmax over 2048 keys per selected row ----------------
__global__ __launch_bounds__(256) void softmax_kernel(float* __restrict__ attn)
{
  __shared__ float buf[KVN];
  __shared__ float red[256];
  const int t = threadIdx.x;
  float* row = attn + (size_t)blockIdx.x * KVN;

  float m = -INFINITY;
  for (int i = t; i < KVN; i += 256) { float v = row[i]; buf[i] = v; m = fmaxf(m, v); }
  red[t] = m;
  __syncthreads();
  for (int off = 128; off > 0; off >>= 1) {
    if (t < off) red[t] = fmaxf(red[t], red[t + off]);
    __syncthreads();
  }
  m = red[0];
  __syncthreads();

  const float sc = 0.022097086912079608f;   // 1/sqrt(2048)
  float s = 0.f;
  for (int i = t; i < KVN; i += 256) { float e = __expf((buf[i] - m) * sc); buf[i] = e; s += e; }
  red[t] = s;
  __syncthreads();
  for (int off = 128; off > 0; off >>= 1) {
    if (t < off) red[t] += red[t + off];
    __syncthreads();
  }
  float inv = 1.f / red[0];
  for (int i = t; i < KVN; i += 256) row[i] = buf[i] * inv;
}

// ---------------- s1 partials = attn @ v, float4 per lane, 32 kv-splits ----------
// grid (2 d-halves, BATCH, S1KS); block 256 = 64 dv4 x 4 j-groups (15 j each).
__global__ __launch_bounds__(256) void s1_partial_kernel(
    const float* __restrict__ attn, const float* __restrict__ v, float* __restrict__ part)
{
  __shared__ float a_s[64][61];     // [kv-local][j], padded: stride 61 is odd
  const int t    = threadIdx.x;
  const int dv4  = t & 63;          // float4 column within the d-half
  const int jg   = t >> 6;          // 0..3 -> j in [jg*15, jg*15+15)
  const int dh   = blockIdx.x;      // d-half: 0 or 1
  const int b    = blockIdx.y;
  const int ks   = blockIdx.z;      // kv split
  const int kv0  = ks * 64;
  const int dbase = dh * 256 + dv4 * 4;

  // stage attn tile: 60 j x 64 kv, coalesced along kv
  for (int x = t; x < NSEL * 64; x += 256) {
    const int j = x >> 6, kk = x & 63;
    a_s[kk][j] = attn[((size_t)(b * NSEL + j)) * KVN + kv0 + kk];
  }
  __syncthreads();

  f32x4 acc[15];
#pragma unroll
  for (int i = 0; i < 15; ++i) { acc[i][0] = 0.f; acc[i][1] = 0.f; acc[i][2] = 0.f; acc[i][3] = 0.f; }

  const float* vb = v + ((size_t)b * KVN + kv0) * DN + dbase;
#pragma unroll 8
  for (int kk = 0; kk < 64; ++kk) {
    const f32x4 vv = *reinterpret_cast<const f32x4*>(vb + (size_t)kk * DN);
#pragma unroll
    for (int jj = 0; jj < 15; ++jj) {
      const float a = a_s[kk][jg * 15 + jj];   // wave-uniform broadcast
      acc[jj][0] = fmaf(a, vv[0], acc[jj][0]);
      acc[jj][1] = fmaf(a, vv[1], acc[jj][1]);
      acc[jj][2] = fmaf(a, vv[2], acc[jj][2]);
      acc[jj][3] = fmaf(a, vv[3], acc[jj][3]);
    }
  }

#pragma unroll
  for (int jj = 0; jj < 15; ++jj) {
    const int j = jg * 15 + jj;
    *reinterpret_cast<f32x4*>(
        part + ((size_t)((ks * BATCH + b) * NSEL) + j) * DN + dbase) = acc[jj];
  }
}

// ---------------- v mean (2-stage) ----------------
__global__ __launch_bounds__(256) void vmean_part_kernel(
    const float* __restrict__ v, float* __restrict__ vpart)
{
  const int t = threadIdx.x;
  const int c = blockIdx.x;   // 0..15
  const int b = blockIdx.y;
  const int kv0 = c * 128;
  for (int d = t; d < DN; d += 256) {
    float s = 0.f;
    for (int r = 0; r < 128; ++r) s += v[((size_t)b * KVN + kv0 + r) * DN + d];
    vpart[(size_t)(c * BATCH + b) * DN + d] = s;
  }
}

__global__ void vmean_combine_kernel(const float* __restrict__ vpart, float* __restrict__ vmean)
{
  int idx = blockIdx.x * 256 + threadIdx.x;   // 0..2047
  if (idx < BATCH * DN) {
    int b = idx / DN, d = idx % DN;
    float s = 0.f;
    for (int c = 0; c < 16; ++c) s += vpart[(size_t)(c * BATCH + b) * DN + d];
    vmean[idx] = s * (1.0f / (float)KVN);
  }
}

// ---------------- fill output with v-mean ----------------
__global__ __launch_bounds__(256) void fill_kernel(
    const float* __restrict__ vmean, float* __restrict__ out)
{
  size_t gid = (size_t)blockIdx.x * 256 + threadIdx.x;   // float4 index
  size_t e = gid * 4;
  int b = (int)(e >> 20);          // Q*D = 1<<20 per batch
  int d = (int)(e & (DN - 1));
  float4 mv = *reinterpret_cast<const float4*>(vmean + b * DN + d);
  *reinterpret_cast<float4*>(out + e) = mv;
}

// ---------------- combine s1 partials & scatter to selected rows ----------------
__global__ void scatter_kernel(const float* __restrict__ part,
                               const int* __restrict__ topidx, float* __restrict__ out)
{
  const int t = threadIdx.x;   // 128
  const int j = blockIdx.x;    // 0..59
  const int b = blockIdx.y;
  const int row = topidx[b * 64 + j];
  const int d = t * 4;
  float4 s = make_float4(0.f, 0.f, 0.f, 0.f);
  for (int sp = 0; sp < S1KS; ++sp) {
    float4 p = *reinterpret_cast<const float4*>(
        part + ((size_t)((sp * BATCH + b) * NSEL) + j) * DN + d);
    s.x += p.x; s.y += p.y; s.z += p.z; s.w += p.w;
  }
  *reinterpret_cast<float4*>(out + ((size_t)b * QN + row) * DN + d) = s;
}

// ---------------- launcher ----------------
extern "C" void kernel_launch(void* const* d_in, const int* in_sizes, int n_in,
                              void* d_out, int out_size, void* d_ws, size_t ws_size,
                              hipStream_t stream) {
  const float* q    = (const float*)d_in[0];
  const float* k    = (const float*)d_in[1];
  const float* v    = (const float*)d_in[2];
  const int*   sidx = (const int*)d_in[3];
  float* out = (float*)d_out;
  char*  W   = (char*)d_ws;

  // region A [0, 32 MB): bf16 splits (dead after s_mfma_kernel)
  const size_t NEL = (size_t)BATCH * QN * DN;   // 4,194,304
  unsigned short* qh = (unsigned short*)W;
  unsigned short* ql = qh + NEL;
  unsigned short* kh = ql + NEL;
  unsigned short* kl = kh + NEL;

  // region B [32 MB, ~34.2 MB): live across phase boundary
  char* W2 = W + 4 * NEL * sizeof(unsigned short);
  float* cnt    = (float*)W2;                         // 32 KB
  float* Pmax   = (float*)(W2 + 32768);               // 1 MB
  float* Psum   = (float*)(W2 + 32768 + 1048576);     // 1 MB
  float* Mbuf   = (float*)(W2 + 32768 + 2097152);     // 32 KB
  int*   topidx = (int*)(W2 + 32768 + 2097152 + 32768); // 1 KB

  // post-phase-1 buffers aliased into region A (splits are dead by then)
  float* qbar  = (float*)W;                  // 512 KB
  float* attn  = (float*)(W + 524288);       // 1.875 MB
  float* part  = (float*)(W + 2490368);      // 32*4*60*512*4 = 15.0 MB
  float* vpart = (float*)(W + 18219008);     // 128 KB
  float* vmean = (float*)(W + 18350080);     // 8 KB -> ends 18.4 MB < 32 MB

  split_kernel<<<dim3(8192), 256, 0, stream>>>(q, k, qh, ql, kh, kl);
  count_kernel<<<dim3(BATCH), 256, 0, stream>>>(sidx, cnt);
  s_mfma_kernel<<<dim3(512), 256, 0, stream>>>(qh, ql, kh, kl, cnt, Pmax, Psum);
  combine_kernel<<<dim3(BATCH * QN / 256), 256, 0, stream>>>(Pmax, Psum, Mbuf);
  select_kernel<<<dim3(BATCH), 256, 0, stream>>>(Mbuf, topidx);
  gather_qbar_kernel<<<dim3(64, BATCH), 128, 0, stream>>>(q, topidx, qbar);
  scores_kernel<<<dim3(KVN / SBN, BATCH), 256, 0, stream>>>(qbar, k, attn);
  softmax_kernel<<<dim3(BATCH * NSEL), 256, 0, stream>>>(attn);
  s1_partial_kernel<<<dim3(2, BATCH, S1KS), 256, 0, stream>>>(attn, v, part);
  vmean_part_kernel<<<dim3(16, BATCH), 256, 0, stream>>>(v, vpart);
  vmean_combine_kernel<<<dim3(8), 256, 0, stream>>>(vpart, vmean);
  fill_kernel<<<dim3(4096), 256, 0, stream>>>(vmean, out);
  scatter_kernel<<<dim3(NSEL, BATCH), 128, 0, stream>>>(part, topidx, out);
}

// Round 7
// 254.948 us; speedup vs baseline: 7.3925x; 1.0164x over previous
//
#include <hip/hip_runtime.h>
#include <math.h>

// Problem constants (B=4, Q=2048, KV=2048, D=512)
#define BATCH 4
#define QN    2048
#define KVN   2048
#define DN    512
#define U_TOT 15615          // int(Q * ln(KV))
#define NSEL  60             // int(8 * ln(Q))
#define NSLOT 32             // 16 j-tiles x 2 n-half waves
#define S1KS  32             // kv-splits for s1 = attn @ v (64 rows each)

typedef __attribute__((ext_vector_type(8))) short bf16x8;
typedef __attribute__((ext_vector_type(4))) float f32x4;

// ---------------- helpers ----------------
__device__ __forceinline__ unsigned short f2bf(float f) {
  unsigned u = __float_as_uint(f);
  unsigned r = (u + 0x7fffu + ((u >> 16) & 1u)) >> 16;   // RNE
  return (unsigned short)r;
}
__device__ __forceinline__ float bf2f(unsigned short h) {
  return __uint_as_float(((unsigned)h) << 16);
}
__device__ __forceinline__ void gld16(const void* g, void* l) {
  __builtin_amdgcn_global_load_lds(
      (const __attribute__((address_space(1))) unsigned int*)g,
      (__attribute__((address_space(3))) unsigned int*)l, 16, 0, 0);
}

// ---------------- split fp32 -> bf16 hi/lo (q and k in one dispatch) ----------------
__global__ __launch_bounds__(256) void split_kernel(
    const float* __restrict__ q, const float* __restrict__ k,
    unsigned short* __restrict__ qhi, unsigned short* __restrict__ qlo,
    unsigned short* __restrict__ khi, unsigned short* __restrict__ klo)
{
  const int half = blockIdx.x >> 12;                       // 0 = q, 1 = k (4096 blocks each)
  const int i = (blockIdx.x & 4095) * 256 + threadIdx.x;   // float4 index
  const float* in = half ? k : q;
  unsigned short* hi = half ? khi : qhi;
  unsigned short* lo = half ? klo : qlo;
  float4 f = reinterpret_cast<const float4*>(in)[i];
  ushort4 h, l;
  h.x = f2bf(f.x); l.x = f2bf(f.x - bf2f(h.x));
  h.y = f2bf(f.y); l.y = f2bf(f.y - bf2f(h.y));
  h.z = f2bf(f.z); l.z = f2bf(f.z - bf2f(h.z));
  h.w = f2bf(f.w); l.w = f2bf(f.w - bf2f(h.w));
  reinterpret_cast<ushort4*>(hi)[i] = h;
  reinterpret_cast<ushort4*>(lo)[i] = l;
}

// ---------------- counts histogram: cnt[b][j] = multiplicity of key j ----------------
__global__ __launch_bounds__(1024) void count_kernel(
    const int* __restrict__ sidx, float* __restrict__ cnt)
{
  __shared__ int h[KVN];
  const int b = blockIdx.x, t = threadIdx.x;
  for (int i = t; i < KVN; i += 1024) h[i] = 0;
  __syncthreads();
  for (int i = t; i < U_TOT; i += 1024) atomicAdd(&h[sidx[b * U_TOT + i]], 1);
  __syncthreads();
  for (int i = t; i < KVN; i += 1024) cnt[b * KVN + i] = (float)h[i];
}

// ---------------- Phase 1: dense S = q @ k^T with fused masked-max / weighted-sum ----
// Staging permutation: lane t fetches row ((t>>6)<<4)|(t&15), chunk (t>>4)&3 of the
// 64-row half-tile -> fragment reads become lane-linear (bank-conflict-free).
// LDS unit (8 shorts) of (row m, chunk c) = (m>>4)*64 + c*16 + (m&15) [+256 for m>=64].
__global__ __launch_bounds__(256) void s_mfma_kernel(
    const unsigned short* __restrict__ qh, const unsigned short* __restrict__ ql,
    const unsigned short* __restrict__ kh, const unsigned short* __restrict__ kl,
    const float* __restrict__ cnt, float* __restrict__ Pmax, float* __restrict__ Psum)
{
  __shared__ unsigned short Ah[128 * 32];
  __shared__ unsigned short Al[128 * 32];
  __shared__ unsigned short Bh[128 * 32];
  __shared__ unsigned short Bl[128 * 32];
  __shared__ float cnt_s[128];

  const int t = threadIdx.x;
  const int w = t >> 6;          // wave 0..3
  const int L = t & 63;
  const int mbase = (w & 1) * 64;
  const int nbase = (w >> 1) * 64;
  const int lm = L & 15;

  // XCD swizzle: xcd = bid&7 -> batch = xcd>>1, j-half = xcd&1
  const int bid = blockIdx.x;
  const int xcd = bid & 7;
  const int idx = bid >> 3;      // 0..63
  const int b   = xcd >> 1;
  const int ji  = (xcd & 1) * 8 + (idx >> 3);   // 0..15
  const int qi0 = (idx & 7) * 2;                // q-tile pair
  const int j0  = ji * 128;

  if (t < 128) cnt_s[t] = cnt[b * KVN + j0 + t];

  // staged row/chunk for this lane (new permutation)
  const int srow = ((t >> 6) << 4) | (t & 15);   // 0..63
  const int schk = (t >> 4) & 3;                 // 0..3

  const size_t koff0 = ((size_t)(b * KVN) + j0 + srow) * DN + (size_t)(schk * 8);
  const size_t koff1 = koff0 + (size_t)64 * DN;

  for (int qq = 0; qq < 2; ++qq) {
    const int q0 = (qi0 + qq) * 128;
    const size_t qoff0 = ((size_t)(b * QN) + q0 + srow) * DN + (size_t)(schk * 8);
    const size_t qoff1 = qoff0 + (size_t)64 * DN;

    f32x4 acc[4][4];   // [nf][mf]
#pragma unroll
    for (int nf = 0; nf < 4; ++nf)
#pragma unroll
      for (int mf = 0; mf < 4; ++mf) {
        acc[nf][mf][0] = 0.f; acc[nf][mf][1] = 0.f;
        acc[nf][mf][2] = 0.f; acc[nf][mf][3] = 0.f;
      }

    for (int d0 = 0; d0 < DN; d0 += 32) {
      __syncthreads();   // LDS reads from previous step done
      gld16(qh + qoff0 + d0, &Ah[t * 8]);
      gld16(qh + qoff1 + d0, &Ah[(t + 256) * 8]);
      gld16(ql + qoff0 + d0, &Al[t * 8]);
      gld16(ql + qoff1 + d0, &Al[(t + 256) * 8]);
      gld16(kh + koff0 + d0, &Bh[t * 8]);
      gld16(kh + koff1 + d0, &Bh[(t + 256) * 8]);
      gld16(kl + koff0 + d0, &Bl[t * 8]);
      gld16(kl + koff1 + d0, &Bl[(t + 256) * 8]);
      __syncthreads();

      // fragment LDS offsets (shorts): (mbase*4 + mf*64 + (L>>4)*16 + lm) * 8
      bf16x8 ah[4], al[4];
#pragma unroll
      for (int mf = 0; mf < 4; ++mf) {
        const int off = (mbase * 4 + mf * 64 + (L >> 4) * 16 + lm) * 8;
        ah[mf] = *reinterpret_cast<const bf16x8*>(&Ah[off]);
        al[mf] = *reinterpret_cast<const bf16x8*>(&Al[off]);
      }
#pragma unroll
      for (int nf = 0; nf < 4; ++nf) {
        const int boff = (nbase * 4 + nf * 64 + (L >> 4) * 16 + lm) * 8;
        bf16x8 bh = *reinterpret_cast<const bf16x8*>(&Bh[boff]);
        bf16x8 bl = *reinterpret_cast<const bf16x8*>(&Bl[boff]);
#pragma unroll
        for (int mf = 0; mf < 4; ++mf) {
          acc[nf][mf] = __builtin_amdgcn_mfma_f32_16x16x32_bf16(ah[mf], bh, acc[nf][mf], 0, 0, 0);
          acc[nf][mf] = __builtin_amdgcn_mfma_f32_16x16x32_bf16(ah[mf], bl, acc[nf][mf], 0, 0, 0);
          acc[nf][mf] = __builtin_amdgcn_mfma_f32_16x16x32_bf16(al[mf], bh, acc[nf][mf], 0, 0, 0);
        }
      }
    }

    // fused epilogue: masked max + count-weighted sum over this j-tile
    // C/D map: j(col) = lane&15, q(row) = (lane>>4)*4 + reg  [m89-verified]
    float mx[4][4], wsm[4][4];
#pragma unroll
    for (int mf = 0; mf < 4; ++mf)
#pragma unroll
      for (int r = 0; r < 4; ++r) { mx[mf][r] = -INFINITY; wsm[mf][r] = 0.f; }

#pragma unroll
    for (int nf = 0; nf < 4; ++nf) {
      const float c = cnt_s[nbase + nf * 16 + lm];
      const bool has = (c > 0.f);
#pragma unroll
      for (int mf = 0; mf < 4; ++mf)
#pragma unroll
        for (int r = 0; r < 4; ++r) {
          const float v = acc[nf][mf][r];
          if (has) mx[mf][r] = fmaxf(mx[mf][r], v);
          wsm[mf][r] = fmaf(c, v, wsm[mf][r]);
        }
    }

    const size_t spi = (size_t)((ji * 2 + (w >> 1)) * BATCH + b);
#pragma unroll
    for (int mf = 0; mf < 4; ++mf)
#pragma unroll
      for (int r = 0; r < 4; ++r) {
        float m = mx[mf][r], s = wsm[mf][r];
#pragma unroll
        for (int o = 1; o < 16; o <<= 1) {
          m = fmaxf(m, __shfl_xor(m, o));
          s += __shfl_xor(s, o);
        }
        if (lm == 0) {
          const int qrow = q0 + mbase + mf * 16 + (L >> 4) * 4 + r;
          Pmax[spi * QN + qrow] = m;
          Psum[spi * QN + qrow] = s;
        }
      }
  }
}

// ---------------- Phase 2a: wide combine of the 32 partial slots -> M[b][q] --------
__global__ __launch_bounds__(256) void combine_kernel(
    const float* __restrict__ Pmax, const float* __restrict__ Psum, float* __restrict__ M)
{
  const int g = blockIdx.x * 256 + threadIdx.x;   // 0 .. BATCH*QN-1
  const int b = g >> 11;                          // QN = 2048
  const int qq = g & (QN - 1);
  float m = -INFINITY, s = 0.f;
#pragma unroll 4
  for (int p = 0; p < NSLOT; ++p) {
    m = fmaxf(m, Pmax[((size_t)(p * BATCH + b)) * QN + qq]);
    s += Psum[((size_t)(p * BATCH + b)) * QN + qq];
  }
  M[g] = m - s * (1.0f / (float)U_TOT);
}

// ---------------- Phase 2b: top-60 SET via MSB-first radix rank-select -----------
// Emits compact topidx (arbitrary order) AND rowslot[b][q] (slot or -1).
__global__ __launch_bounds__(256) void select_kernel(
    const float* __restrict__ M, int* __restrict__ topidx, int* __restrict__ rowslot)
{
  const int b = blockIdx.x;
  const int t = threadIdx.x;
  unsigned long long key[8];
#pragma unroll
  for (int s = 0; s < 8; ++s) {
    const int qq = s * 256 + t;
    unsigned u = __float_as_uint(M[b * QN + qq]);
    u = (u & 0x80000000u) ? ~u : (u | 0x80000000u);   // order-preserving map
    key[s] = ((unsigned long long)u << 32) | (unsigned)(QN - qq);
    rowslot[b * QN + qq] = -1;
  }

  __shared__ unsigned hist[256];
  __shared__ unsigned long long pref_s;
  __shared__ unsigned rank_s;
  __shared__ unsigned cnt_s;
  if (t == 0) { pref_s = 0ull; rank_s = NSEL; cnt_s = 0u; }
  __syncthreads();

  for (int level = 7; level >= 0; --level) {
    const int shift = level * 8;
    hist[t] = 0;
    __syncthreads();
    const unsigned long long pref = pref_s;
    const unsigned rank = rank_s;
#pragma unroll
    for (int s = 0; s < 8; ++s) {
      const bool match = (level == 7) || ((key[s] >> (shift + 8)) == pref);
      if (match) atomicAdd(&hist[(unsigned)((key[s] >> shift) & 255u)], 1u);
    }
    __syncthreads();
    if (t < 64) {   // wave 0: suffix-scan 256 buckets, 4 per lane
      const unsigned h0 = hist[4 * t], h1 = hist[4 * t + 1];
      const unsigned h2 = hist[4 * t + 2], h3 = hist[4 * t + 3];
      const unsigned loc = h0 + h1 + h2 + h3;
      unsigned run = loc;   // -> sum over lanes >= t
#pragma unroll
      for (int o = 1; o < 64; o <<= 1) {
        const unsigned oth = (unsigned)__shfl_down((int)run, o);
        if (t + o < 64) run += oth;
      }
      const unsigned suf = run - loc;       // cumGT past this lane's buckets
      const unsigned c3 = suf, c2 = c3 + h3, c1 = c2 + h2, c0 = c1 + h1;
      int hit = -1; unsigned cgt = 0;
      if      (c3 < rank && rank <= c3 + h3) { hit = 4 * t + 3; cgt = c3; }
      else if (c2 < rank && rank <= c2 + h2) { hit = 4 * t + 2; cgt = c2; }
      else if (c1 < rank && rank <= c1 + h1) { hit = 4 * t + 1; cgt = c1; }
      else if (c0 < rank && rank <= c0 + h0) { hit = 4 * t + 0; cgt = c0; }
      if (hit >= 0) {   // exactly one lane
        pref_s = ((level == 7) ? 0ull : (pref_s << 8)) | (unsigned long long)(unsigned)hit;
        rank_s = rank - cgt;
      }
    }
    __syncthreads();
  }

  const unsigned long long T = pref_s;   // 60th-largest key
#pragma unroll
  for (int s = 0; s < 8; ++s) {
    if (key[s] >= T) {
      const unsigned pos = atomicAdd(&cnt_s, 1u);
      const int qsel = QN - (int)(key[s] & 0xFFFFFFFFull);
      topidx[b * 64 + pos] = qsel;
      rowslot[b * QN + qsel] = (int)pos;
    }
  }
}

// ---------------- scores = q_bar @ k^T with inline q gather (raw, fp32) ----------
#define SBM 64
#define SBN 64
#define SBK 32
__global__ __launch_bounds__(256) void scores_kernel(
    const float* __restrict__ q, const int* __restrict__ topidx,
    const float* __restrict__ k, float* __restrict__ attn)
{
  __shared__ float a_s[SBK][SBM + 4];
  __shared__ float b_s[SBK][SBN + 4];
  __shared__ int tix_s[64];
  const int t  = threadIdx.x;
  const int tx = t & 15, ty = t >> 4;
  const int kv0 = blockIdx.x * SBN;
  const int b   = blockIdx.y;
  const float* kb = k + (size_t)b * KVN * DN;

  if (t < 64) tix_s[t] = (t < NSEL) ? topidx[b * 64 + t] : 0;
  __syncthreads();

  float acc[4][4];
#pragma unroll
  for (int i = 0; i < 4; ++i)
#pragma unroll
    for (int j = 0; j < 4; ++j) acc[i][j] = 0.f;

  const int c4 = (t & 7) * 4;
  const int r0 = t >> 3;   // 0..31
  const int srow0 = tix_s[r0];
  const int srow1 = tix_s[r0 + 32];

  for (int d0 = 0; d0 < DN; d0 += SBK) {
#pragma unroll
    for (int rr = 0; rr < 2; ++rr) {
      int row = r0 + rr * 32;
      int srow = rr ? srow1 : srow0;
      float4 av = *reinterpret_cast<const float4*>(q + ((size_t)(b * QN) + srow) * DN + d0 + c4);
      a_s[c4 + 0][row] = av.x; a_s[c4 + 1][row] = av.y;
      a_s[c4 + 2][row] = av.z; a_s[c4 + 3][row] = av.w;
      float4 bv = *reinterpret_cast<const float4*>(kb + (size_t)(kv0 + row) * DN + d0 + c4);
      b_s[c4 + 0][row] = bv.x; b_s[c4 + 1][row] = bv.y;
      b_s[c4 + 2][row] = bv.z; b_s[c4 + 3][row] = bv.w;
    }
    __syncthreads();
#pragma unroll
    for (int kk = 0; kk < SBK; ++kk) {
      float4 av = *reinterpret_cast<const float4*>(&a_s[kk][ty * 4]);
      float4 bv = *reinterpret_cast<const float4*>(&b_s[kk][tx * 4]);
      float af[4] = {av.x, av.y, av.z, av.w};
      float bf[4] = {bv.x, bv.y, bv.z, bv.w};
#pragma unroll
      for (int i = 0; i < 4; ++i)
#pragma unroll
        for (int j = 0; j < 4; ++j)
          acc[i][j] = fmaf(af[i], bf[j], acc[i][j]);
    }
    __syncthreads();
  }

#pragma unroll
  for (int i = 0; i < 4; ++i) {
    int j = ty * 4 + i;
    if (j < NSEL) {
      float4 o = make_float4(acc[i][0], acc[i][1], acc[i][2], acc[i][3]);
      *reinterpret_cast<float4*>(attn + ((size_t)(b * NSEL + j)) * KVN + kv0 + tx * 4) = o;
    }
  }
}

// ---------------- softmax over 2048 keys per selected row ----------------
__global__ __launch_bounds__(256) void softmax_kernel(float* __restrict__ attn)
{
  __shared__ float buf[KVN];
  __shared__ float red[256];
  const int t = threadIdx.x;
  float* row = attn + (size_t)blockIdx.x * KVN;

  float m = -INFINITY;
  for (int i = t; i < KVN; i += 256) { float v = row[i]; buf[i] = v; m = fmaxf(m, v); }
  red[t] = m;
  __syncthreads();
  for (int off = 128; off > 0; off >>= 1) {
    if (t < off) red[t] = fmaxf(red[t], red[t + off]);
    __syncthreads();
  }
  m = red[0];
  __syncthreads();

  const float sc = 0.022097086912079608f;   // 1/sqrt(2048)
  float s = 0.f;
  for (int i = t; i < KVN; i += 256) { float e = __expf((buf[i] - m) * sc); buf[i] = e; s += e; }
  red[t] = s;
  __syncthreads();
  for (int off = 128; off > 0; off >>= 1) {
    if (t < off) red[t] += red[t + off];
    __syncthreads();
  }
  float inv = 1.f / red[0];
  for (int i = t; i < KVN; i += 256) row[i] = buf[i] * inv;
}

// ---------------- s1 partials = attn @ v + fused v-column partial sums -----------
// grid (2 d-halves, BATCH, S1KS); block 256 = 64 dv4 x 4 j-groups (15 j each).
// wave 0 (jg==0) also accumulates the v column sums for the mean (free reads).
__global__ __launch_bounds__(256) void s1_partial_kernel(
    const float* __restrict__ attn, const float* __restrict__ v,
    float* __restrict__ part, float* __restrict__ vpart)
{
  __shared__ float a_s[64][61];     // [kv-local][j], padded: stride 61 is odd
  const int t    = threadIdx.x;
  const int dv4  = t & 63;          // float4 column within the d-half
  const int jg   = t >> 6;          // 0..3 -> j in [jg*15, jg*15+15)
  const int dh   = blockIdx.x;      // d-half: 0 or 1
  const int b    = blockIdx.y;
  const int ks   = blockIdx.z;      // kv split
  const int kv0  = ks * 64;
  const int dbase = dh * 256 + dv4 * 4;

  // stage attn tile: 60 j x 64 kv, coalesced along kv
  for (int x = t; x < NSEL * 64; x += 256) {
    const int j = x >> 6, kk = x & 63;
    a_s[kk][j] = attn[((size_t)(b * NSEL + j)) * KVN + kv0 + kk];
  }
  __syncthreads();

  f32x4 acc[15];
#pragma unroll
  for (int i = 0; i < 15; ++i) { acc[i][0] = 0.f; acc[i][1] = 0.f; acc[i][2] = 0.f; acc[i][3] = 0.f; }
  f32x4 vsum; vsum[0] = 0.f; vsum[1] = 0.f; vsum[2] = 0.f; vsum[3] = 0.f;

  const float* vb = v + ((size_t)b * KVN + kv0) * DN + dbase;
#pragma unroll 8
  for (int kk = 0; kk < 64; ++kk) {
    const f32x4 vv = *reinterpret_cast<const f32x4*>(vb + (size_t)kk * DN);
    if (jg == 0) { vsum[0] += vv[0]; vsum[1] += vv[1]; vsum[2] += vv[2]; vsum[3] += vv[3]; }
#pragma unroll
    for (int jj = 0; jj < 15; ++jj) {
      const float a = a_s[kk][jg * 15 + jj];   // wave-uniform broadcast
      acc[jj][0] = fmaf(a, vv[0], acc[jj][0]);
      acc[jj][1] = fmaf(a, vv[1], acc[jj][1]);
      acc[jj][2] = fmaf(a, vv[2], acc[jj][2]);
      acc[jj][3] = fmaf(a, vv[3], acc[jj][3]);
    }
  }

#pragma unroll
  for (int jj = 0; jj < 15; ++jj) {
    const int j = jg * 15 + jj;
    *reinterpret_cast<f32x4*>(
        part + ((size_t)((ks * BATCH + b) * NSEL) + j) * DN + dbase) = acc[jj];
  }
  if (jg == 0)
    *reinterpret_cast<f32x4*>(vpart + ((size_t)(ks * BATCH + b)) * DN + dbase) = vsum;
}

// ---------------- combine v partial sums -> vmean ----------------
__global__ void vmean_combine_kernel(const float* __restrict__ vpart, float* __restrict__ vmean)
{
  int idx = blockIdx.x * 256 + threadIdx.x;   // 0..2047
  if (idx < BATCH * DN) {
    int b = idx / DN, d = idx % DN;
    float s = 0.f;
    for (int c = 0; c < S1KS; ++c) s += vpart[(size_t)(c * BATCH + b) * DN + d];
    vmean[idx] = s * (1.0f / (float)KVN);
  }
}

// ---------------- output: v-mean fill + s1 scatter in one pass ----------------
__global__ __launch_bounds__(256) void out_kernel(
    const float* __restrict__ part, const float* __restrict__ vmean,
    const int* __restrict__ rowslot, float* __restrict__ out)
{
  const int gid = blockIdx.x * 256 + threadIdx.x;   // float4 index, 0..1048575
  const int d4 = gid & 127;
  const int qq = (gid >> 7) & (QN - 1);
  const int b  = gid >> 18;                          // QN*DN/4 = 2^18
  const int slot = rowslot[b * QN + qq];
  f32x4 o;
  if (slot >= 0) {
    o[0] = 0.f; o[1] = 0.f; o[2] = 0.f; o[3] = 0.f;
    for (int ks = 0; ks < S1KS; ++ks) {
      const f32x4 p = reinterpret_cast<const f32x4*>(part)[
          ((size_t)((ks * BATCH + b) * NSEL) + slot) * (DN / 4) + d4];
      o[0] += p[0]; o[1] += p[1]; o[2] += p[2]; o[3] += p[3];
    }
  } else {
    o = reinterpret_cast<const f32x4*>(vmean)[b * (DN / 4) + d4];
  }
  reinterpret_cast<f32x4*>(out)[gid] = o;
}

// ---------------- launcher ----------------
extern "C" void kernel_launch(void* const* d_in, const int* in_sizes, int n_in,
                              void* d_out, int out_size, void* d_ws, size_t ws_size,
                              hipStream_t stream) {
  const float* q    = (const float*)d_in[0];
  const float* k    = (const float*)d_in[1];
  const float* v    = (const float*)d_in[2];
  const int*   sidx = (const int*)d_in[3];
  float* out = (float*)d_out;
  char*  W   = (char*)d_ws;

  // region A [0, 32 MB): bf16 splits (dead after s_mfma_kernel)
  const size_t NEL = (size_t)BATCH * QN * DN;   // 4,194,304
  unsigned short* qh = (unsigned short*)W;
  unsigned short* ql = qh + NEL;
  unsigned short* kh = ql + NEL;
  unsigned short* kl = kh + NEL;

  // region B [32 MB, ~34.2 MB): live across phase boundary
  char* W2 = W + 4 * NEL * sizeof(unsigned short);
  float* cnt     = (float*)W2;                          // 32 KB
  float* Pmax    = (float*)(W2 + 32768);                // 1 MB
  float* Psum    = (float*)(W2 + 32768 + 1048576);      // 1 MB
  float* Mbuf    = (float*)(W2 + 32768 + 2097152);      // 32 KB
  int*   topidx  = (int*)(W2 + 32768 + 2097152 + 32768);          // 4 KB
  int*   rowslot = (int*)(W2 + 32768 + 2097152 + 32768 + 4096);   // 32 KB

  // post-phase-1 buffers aliased into region A (splits are dead by then)
  float* attn  = (float*)W;                  // 1.875 MB
  float* part  = (float*)(W + 2097152);      // 32*4*60*512*4 = 15.0 MB
  float* vpart = (float*)(W + 17825792);     // 256 KB
  float* vmean = (float*)(W + 18087936);     // 8 KB -> ends ~18.1 MB < 32 MB

  split_kernel<<<dim3(8192), 256, 0, stream>>>(q, k, qh, ql, kh, kl);
  count_kernel<<<dim3(BATCH), 1024, 0, stream>>>(sidx, cnt);
  s_mfma_kernel<<<dim3(512), 256, 0, stream>>>(qh, ql, kh, kl, cnt, Pmax, Psum);
  combine_kernel<<<dim3(BATCH * QN / 256), 256, 0, stream>>>(Pmax, Psum, Mbuf);
  select_kernel<<<dim3(BATCH), 256, 0, stream>>>(Mbuf, topidx, rowslot);
  scores_kernel<<<dim3(KVN / SBN, BATCH), 256, 0, stream>>>(q, topidx, k, attn);
  softmax_kernel<<<dim3(BATCH * NSEL), 256, 0, stream>>>(attn);
  s1_partial_kernel<<<dim3(2, BATCH, S1KS), 256, 0, stream>>>(attn, v, part, vpart);
  vmean_combine_kernel<<<dim3(8), 256, 0, stream>>>(vpart, vmean);
  out_kernel<<<dim3(4096), 256, 0, stream>>>(part, vmean, rowslot, out);
}

// Round 8
// 233.232 us; speedup vs baseline: 8.0808x; 1.0931x over previous
//
#include <hip/hip_runtime.h>
#include <math.h>

// Problem constants (B=4, Q=2048, KV=2048, D=512)
#define BATCH 4
#define QN    2048
#define KVN   2048
#define DN    512
#define U_TOT 15615          // int(Q * ln(KV))
#define NSEL  60             // int(8 * ln(Q))
#define NSLOT 32             // 16 j-tiles x 2 n-half waves
#define S1KS  64             // kv-splits for s1 = attn @ v (32 rows each)

typedef __attribute__((ext_vector_type(8))) short bf16x8;
typedef __attribute__((ext_vector_type(4))) float f32x4;

// ---------------- helpers ----------------
__device__ __forceinline__ unsigned short f2bf(float f) {
  unsigned u = __float_as_uint(f);
  unsigned r = (u + 0x7fffu + ((u >> 16) & 1u)) >> 16;   // RNE
  return (unsigned short)r;
}
__device__ __forceinline__ float bf2f(unsigned short h) {
  return __uint_as_float(((unsigned)h) << 16);
}
__device__ __forceinline__ void gld16(const void* g, void* l) {
  __builtin_amdgcn_global_load_lds(
      (const __attribute__((address_space(1))) unsigned int*)g,
      (__attribute__((address_space(3))) unsigned int*)l, 16, 0, 0);
}

// ---------------- split fp32 -> bf16 hi/lo (q and k in one dispatch) ----------------
__global__ __launch_bounds__(256) void split_kernel(
    const float* __restrict__ q, const float* __restrict__ k,
    unsigned short* __restrict__ qhi, unsigned short* __restrict__ qlo,
    unsigned short* __restrict__ khi, unsigned short* __restrict__ klo)
{
  const int half = blockIdx.x >> 12;                       // 0 = q, 1 = k (4096 blocks each)
  const int i = (blockIdx.x & 4095) * 256 + threadIdx.x;   // float4 index
  const float* in = half ? k : q;
  unsigned short* hi = half ? khi : qhi;
  unsigned short* lo = half ? klo : qlo;
  float4 f = reinterpret_cast<const float4*>(in)[i];
  ushort4 h, l;
  h.x = f2bf(f.x); l.x = f2bf(f.x - bf2f(h.x));
  h.y = f2bf(f.y); l.y = f2bf(f.y - bf2f(h.y));
  h.z = f2bf(f.z); l.z = f2bf(f.z - bf2f(h.z));
  h.w = f2bf(f.w); l.w = f2bf(f.w - bf2f(h.w));
  reinterpret_cast<ushort4*>(hi)[i] = h;
  reinterpret_cast<ushort4*>(lo)[i] = l;
}

// ---------------- counts histogram: cnt[b][j] = multiplicity of key j ----------------
__global__ __launch_bounds__(1024) void count_kernel(
    const int* __restrict__ sidx, float* __restrict__ cnt)
{
  __shared__ int h[KVN];
  const int b = blockIdx.x, t = threadIdx.x;
  for (int i = t; i < KVN; i += 1024) h[i] = 0;
  __syncthreads();
  for (int i = t; i < U_TOT; i += 1024) atomicAdd(&h[sidx[b * U_TOT + i]], 1);
  __syncthreads();
  for (int i = t; i < KVN; i += 1024) cnt[b * KVN + i] = (float)h[i];
}

// ---------------- Phase 1: dense S = q @ k^T with fused masked-max / weighted-sum ----
// XOR chunk-swizzle staging: lane t stages row r = t>>2, chunk c = (t&3) ^ ((t>>3)&3)
//  -> lanes 4a..4a+3 still cover one contiguous 64 B row segment (coalesced), AND
//  fragment unit u(m,c) = 4m + (c ^ ((m>>1)&3)) has bank residues covering all 8
//  twice per 16-lane quad -> 2-way LDS access = free.
__global__ __launch_bounds__(256) void s_mfma_kernel(
    const unsigned short* __restrict__ qh, const unsigned short* __restrict__ ql,
    const unsigned short* __restrict__ kh, const unsigned short* __restrict__ kl,
    const float* __restrict__ cnt, float* __restrict__ Pmax, float* __restrict__ Psum)
{
  __shared__ unsigned short Ah[128 * 32];
  __shared__ unsigned short Al[128 * 32];
  __shared__ unsigned short Bh[128 * 32];
  __shared__ unsigned short Bl[128 * 32];
  __shared__ float cnt_s[128];

  const int t = threadIdx.x;
  const int w = t >> 6;          // wave 0..3
  const int L = t & 63;
  const int mbase = (w & 1) * 64;
  const int nbase = (w >> 1) * 64;
  const int lm = L & 15;

  // XCD swizzle: xcd = bid&7 -> batch = xcd>>1, j-half = xcd&1
  const int bid = blockIdx.x;
  const int xcd = bid & 7;
  const int idx = bid >> 3;      // 0..63
  const int b   = xcd >> 1;
  const int ji  = (xcd & 1) * 8 + (idx >> 3);   // 0..15
  const int qi0 = (idx & 7) * 2;                // q-tile pair
  const int j0  = ji * 128;

  if (t < 128) cnt_s[t] = cnt[b * KVN + j0 + t];

  // staging row/chunk (XOR-swizzled, coalesced)
  const int srow = t >> 2;                       // 0..63
  const int schk = (t & 3) ^ ((t >> 3) & 3);     // 0..3

  // fragment LDS base offsets (shorts), K-loop-invariant
  const int perm  = (L >> 4) ^ ((lm >> 1) & 3);  // c ^ s(m), 0..3
  const int abase = (mbase * 4 + lm * 4 + perm) * 8;
  const int bbase = (nbase * 4 + lm * 4 + perm) * 8;

  const size_t koff0 = ((size_t)(b * KVN) + j0 + srow) * DN + (size_t)(schk * 8);
  const size_t koff1 = koff0 + (size_t)64 * DN;

  for (int qq = 0; qq < 2; ++qq) {
    const int q0 = (qi0 + qq) * 128;
    const size_t qoff0 = ((size_t)(b * QN) + q0 + srow) * DN + (size_t)(schk * 8);
    const size_t qoff1 = qoff0 + (size_t)64 * DN;

    f32x4 acc[4][4];   // [nf][mf]
#pragma unroll
    for (int nf = 0; nf < 4; ++nf)
#pragma unroll
      for (int mf = 0; mf < 4; ++mf) {
        acc[nf][mf][0] = 0.f; acc[nf][mf][1] = 0.f;
        acc[nf][mf][2] = 0.f; acc[nf][mf][3] = 0.f;
      }

    for (int d0 = 0; d0 < DN; d0 += 32) {
      __syncthreads();   // LDS reads from previous step done
      gld16(qh + qoff0 + d0, &Ah[t * 8]);
      gld16(qh + qoff1 + d0, &Ah[(t + 256) * 8]);
      gld16(ql + qoff0 + d0, &Al[t * 8]);
      gld16(ql + qoff1 + d0, &Al[(t + 256) * 8]);
      gld16(kh + koff0 + d0, &Bh[t * 8]);
      gld16(kh + koff1 + d0, &Bh[(t + 256) * 8]);
      gld16(kl + koff0 + d0, &Bl[t * 8]);
      gld16(kl + koff1 + d0, &Bl[(t + 256) * 8]);
      __syncthreads();

      bf16x8 ah[4], al[4];
#pragma unroll
      for (int mf = 0; mf < 4; ++mf) {
        ah[mf] = *reinterpret_cast<const bf16x8*>(&Ah[abase + mf * 512]);
        al[mf] = *reinterpret_cast<const bf16x8*>(&Al[abase + mf * 512]);
      }
#pragma unroll
      for (int nf = 0; nf < 4; ++nf) {
        bf16x8 bh = *reinterpret_cast<const bf16x8*>(&Bh[bbase + nf * 512]);
        bf16x8 bl = *reinterpret_cast<const bf16x8*>(&Bl[bbase + nf * 512]);
#pragma unroll
        for (int mf = 0; mf < 4; ++mf) {
          acc[nf][mf] = __builtin_amdgcn_mfma_f32_16x16x32_bf16(ah[mf], bh, acc[nf][mf], 0, 0, 0);
          acc[nf][mf] = __builtin_amdgcn_mfma_f32_16x16x32_bf16(ah[mf], bl, acc[nf][mf], 0, 0, 0);
          acc[nf][mf] = __builtin_amdgcn_mfma_f32_16x16x32_bf16(al[mf], bh, acc[nf][mf], 0, 0, 0);
        }
      }
    }

    // fused epilogue: masked max + count-weighted sum over this j-tile
    // C/D map: j(col) = lane&15, q(row) = (lane>>4)*4 + reg  [m89-verified]
    float mx[4][4], wsm[4][4];
#pragma unroll
    for (int mf = 0; mf < 4; ++mf)
#pragma unroll
      for (int r = 0; r < 4; ++r) { mx[mf][r] = -INFINITY; wsm[mf][r] = 0.f; }

#pragma unroll
    for (int nf = 0; nf < 4; ++nf) {
      const float c = cnt_s[nbase + nf * 16 + lm];
      const bool has = (c > 0.f);
#pragma unroll
      for (int mf = 0; mf < 4; ++mf)
#pragma unroll
        for (int r = 0; r < 4; ++r) {
          const float v = acc[nf][mf][r];
          if (has) mx[mf][r] = fmaxf(mx[mf][r], v);
          wsm[mf][r] = fmaf(c, v, wsm[mf][r]);
        }
    }

    const size_t spi = (size_t)((ji * 2 + (w >> 1)) * BATCH + b);
#pragma unroll
    for (int mf = 0; mf < 4; ++mf)
#pragma unroll
      for (int r = 0; r < 4; ++r) {
        float m = mx[mf][r], s = wsm[mf][r];
#pragma unroll
        for (int o = 1; o < 16; o <<= 1) {
          m = fmaxf(m, __shfl_xor(m, o));
          s += __shfl_xor(s, o);
        }
        if (lm == 0) {
          const int qrow = q0 + mbase + mf * 16 + (L >> 4) * 4 + r;
          Pmax[spi * QN + qrow] = m;
          Psum[spi * QN + qrow] = s;
        }
      }
  }
}

// ---------------- Phase 2a: wide combine of the 32 partial slots -> M[b][q] --------
__global__ __launch_bounds__(256) void combine_kernel(
    const float* __restrict__ Pmax, const float* __restrict__ Psum, float* __restrict__ M)
{
  const int g = blockIdx.x * 256 + threadIdx.x;   // 0 .. BATCH*QN-1
  const int b = g >> 11;                          // QN = 2048
  const int qq = g & (QN - 1);
  float m = -INFINITY, s = 0.f;
#pragma unroll 4
  for (int p = 0; p < NSLOT; ++p) {
    m = fmaxf(m, Pmax[((size_t)(p * BATCH + b)) * QN + qq]);
    s += Psum[((size_t)(p * BATCH + b)) * QN + qq];
  }
  M[g] = m - s * (1.0f / (float)U_TOT);
}

// ---------------- Phase 2b: top-60 SET via MSB-first radix rank-select -----------
// Emits compact topidx (arbitrary order) AND rowslot[b][q] (slot or -1).
__global__ __launch_bounds__(256) void select_kernel(
    const float* __restrict__ M, int* __restrict__ topidx, int* __restrict__ rowslot)
{
  const int b = blockIdx.x;
  const int t = threadIdx.x;
  unsigned long long key[8];
#pragma unroll
  for (int s = 0; s < 8; ++s) {
    const int qq = s * 256 + t;
    unsigned u = __float_as_uint(M[b * QN + qq]);
    u = (u & 0x80000000u) ? ~u : (u | 0x80000000u);   // order-preserving map
    key[s] = ((unsigned long long)u << 32) | (unsigned)(QN - qq);
    rowslot[b * QN + qq] = -1;
  }

  __shared__ unsigned hist[256];
  __shared__ unsigned long long pref_s;
  __shared__ unsigned rank_s;
  __shared__ unsigned cnt_s;
  if (t == 0) { pref_s = 0ull; rank_s = NSEL; cnt_s = 0u; }
  __syncthreads();

  for (int level = 7; level >= 0; --level) {
    const int shift = level * 8;
    hist[t] = 0;
    __syncthreads();
    const unsigned long long pref = pref_s;
    const unsigned rank = rank_s;
#pragma unroll
    for (int s = 0; s < 8; ++s) {
      const bool match = (level == 7) || ((key[s] >> (shift + 8)) == pref);
      if (match) atomicAdd(&hist[(unsigned)((key[s] >> shift) & 255u)], 1u);
    }
    __syncthreads();
    if (t < 64) {   // wave 0: suffix-scan 256 buckets, 4 per lane
      const unsigned h0 = hist[4 * t], h1 = hist[4 * t + 1];
      const unsigned h2 = hist[4 * t + 2], h3 = hist[4 * t + 3];
      const unsigned loc = h0 + h1 + h2 + h3;
      unsigned run = loc;   // -> sum over lanes >= t
#pragma unroll
      for (int o = 1; o < 64; o <<= 1) {
        const unsigned oth = (unsigned)__shfl_down((int)run, o);
        if (t + o < 64) run += oth;
      }
      const unsigned suf = run - loc;       // cumGT past this lane's buckets
      const unsigned c3 = suf, c2 = c3 + h3, c1 = c2 + h2, c0 = c1 + h1;
      int hit = -1; unsigned cgt = 0;
      if      (c3 < rank && rank <= c3 + h3) { hit = 4 * t + 3; cgt = c3; }
      else if (c2 < rank && rank <= c2 + h2) { hit = 4 * t + 2; cgt = c2; }
      else if (c1 < rank && rank <= c1 + h1) { hit = 4 * t + 1; cgt = c1; }
      else if (c0 < rank && rank <= c0 + h0) { hit = 4 * t + 0; cgt = c0; }
      if (hit >= 0) {   // exactly one lane
        pref_s = ((level == 7) ? 0ull : (pref_s << 8)) | (unsigned long long)(unsigned)hit;
        rank_s = rank - cgt;
      }
    }
    __syncthreads();
  }

  const unsigned long long T = pref_s;   // 60th-largest key
#pragma unroll
  for (int s = 0; s < 8; ++s) {
    if (key[s] >= T) {
      const unsigned pos = atomicAdd(&cnt_s, 1u);
      const int qsel = QN - (int)(key[s] & 0xFFFFFFFFull);
      topidx[b * 64 + pos] = qsel;
      rowslot[b * QN + qsel] = (int)pos;
    }
  }
}

// ---------------- scores = q_bar @ k^T with inline q gather (raw, fp32) ----------
// 32-kv tiles -> 256 blocks (1/CU).
#define SBM 64
#define SBN 32
#define SBK 32
__global__ __launch_bounds__(256) void scores_kernel(
    const float* __restrict__ q, const int* __restrict__ topidx,
    const float* __restrict__ k, float* __restrict__ attn)
{
  __shared__ float a_s[SBK][SBM + 4];
  __shared__ float b_s[SBK][SBN + 4];
  __shared__ int tix_s[64];
  const int t  = threadIdx.x;
  const int tx = t & 7;        // 8 col-groups of 4 kv
  const int ty = t >> 3;       // 32 row-groups of 2 q
  const int kv0 = blockIdx.x * SBN;
  const int b   = blockIdx.y;
  const float* kb = k + (size_t)b * KVN * DN;

  if (t < 64) tix_s[t] = (t < NSEL) ? topidx[b * 64 + t] : 0;
  __syncthreads();

  float acc[2][4];
#pragma unroll
  for (int i = 0; i < 2; ++i)
#pragma unroll
    for (int j = 0; j < 4; ++j) acc[i][j] = 0.f;

  const int c4 = (t & 7) * 4;
  const int r0 = t >> 3;   // 0..31
  const int srow0 = tix_s[r0];
  const int srow1 = tix_s[r0 + 32];

  for (int d0 = 0; d0 < DN; d0 += SBK) {
#pragma unroll
    for (int rr = 0; rr < 2; ++rr) {
      int row = r0 + rr * 32;
      int srow = rr ? srow1 : srow0;
      float4 av = *reinterpret_cast<const float4*>(q + ((size_t)(b * QN) + srow) * DN + d0 + c4);
      a_s[c4 + 0][row] = av.x; a_s[c4 + 1][row] = av.y;
      a_s[c4 + 2][row] = av.z; a_s[c4 + 3][row] = av.w;
    }
    {
      float4 bv = *reinterpret_cast<const float4*>(kb + (size_t)(kv0 + r0) * DN + d0 + c4);
      b_s[c4 + 0][r0] = bv.x; b_s[c4 + 1][r0] = bv.y;
      b_s[c4 + 2][r0] = bv.z; b_s[c4 + 3][r0] = bv.w;
    }
    __syncthreads();
#pragma unroll
    for (int kk = 0; kk < SBK; ++kk) {
      const float a0 = a_s[kk][ty * 2];
      const float a1 = a_s[kk][ty * 2 + 1];
      float4 bv = *reinterpret_cast<const float4*>(&b_s[kk][tx * 4]);
      float bf[4] = {bv.x, bv.y, bv.z, bv.w};
#pragma unroll
      for (int j = 0; j < 4; ++j) {
        acc[0][j] = fmaf(a0, bf[j], acc[0][j]);
        acc[1][j] = fmaf(a1, bf[j], acc[1][j]);
      }
    }
    __syncthreads();
  }

#pragma unroll
  for (int i = 0; i < 2; ++i) {
    int j = ty * 2 + i;
    if (j < NSEL) {
      float4 o = make_float4(acc[i][0], acc[i][1], acc[i][2], acc[i][3]);
      *reinterpret_cast<float4*>(attn + ((size_t)(b * NSEL + j)) * KVN + kv0 + tx * 4) = o;
    }
  }
}

// ---------------- softmax over 2048 keys per selected row ----------------
__global__ __launch_bounds__(256) void softmax_kernel(float* __restrict__ attn)
{
  __shared__ float buf[KVN];
  __shared__ float red[256];
  const int t = threadIdx.x;
  float* row = attn + (size_t)blockIdx.x * KVN;

  float m = -INFINITY;
  for (int i = t; i < KVN; i += 256) { float v = row[i]; buf[i] = v; m = fmaxf(m, v); }
  red[t] = m;
  __syncthreads();
  for (int off = 128; off > 0; off >>= 1) {
    if (t < off) red[t] = fmaxf(red[t], red[t + off]);
    __syncthreads();
  }
  m = red[0];
  __syncthreads();

  const float sc = 0.022097086912079608f;   // 1/sqrt(2048)
  float s = 0.f;
  for (int i = t; i < KVN; i += 256) { float e = __expf((buf[i] - m) * sc); buf[i] = e; s += e; }
  red[t] = s;
  __syncthreads();
  for (int off = 128; off > 0; off >>= 1) {
    if (t < off) red[t] += red[t + off];
    __syncthreads();
  }
  float inv = 1.f / red[0];
  for (int i = t; i < KVN; i += 256) row[i] = buf[i] * inv;
}

// ---------------- s1 partials = attn @ v + fused v-column partial sums -----------
// grid (2 d-halves, BATCH, S1KS=64 splits of 32 kv rows); block 256 = 64 dv4 x 4 jg.
__global__ __launch_bounds__(256) void s1_partial_kernel(
    const float* __restrict__ attn, const float* __restrict__ v,
    float* __restrict__ part, float* __restrict__ vpart)
{
  __shared__ float a_s[32][61];     // [kv-local][j], stride 61 odd
  const int t    = threadIdx.x;
  const int dv4  = t & 63;          // float4 column within the d-half
  const int jg   = t >> 6;          // 0..3 -> j in [jg*15, jg*15+15)
  const int dh   = blockIdx.x;      // d-half: 0 or 1
  const int b    = blockIdx.y;
  const int ks   = blockIdx.z;      // kv split
  const int kv0  = ks * 32;
  const int dbase = dh * 256 + dv4 * 4;

  // stage attn tile: 60 j x 32 kv, coalesced along kv
  for (int x = t; x < NSEL * 32; x += 256) {
    const int j = x >> 5, kk = x & 31;
    a_s[kk][j] = attn[((size_t)(b * NSEL + j)) * KVN + kv0 + kk];
  }
  __syncthreads();

  f32x4 acc[15];
#pragma unroll
  for (int i = 0; i < 15; ++i) { acc[i][0] = 0.f; acc[i][1] = 0.f; acc[i][2] = 0.f; acc[i][3] = 0.f; }
  f32x4 vsum; vsum[0] = 0.f; vsum[1] = 0.f; vsum[2] = 0.f; vsum[3] = 0.f;

  const float* vb = v + ((size_t)b * KVN + kv0) * DN + dbase;
#pragma unroll 8
  for (int kk = 0; kk < 32; ++kk) {
    const f32x4 vv = *reinterpret_cast<const f32x4*>(vb + (size_t)kk * DN);
    if (jg == 0) { vsum[0] += vv[0]; vsum[1] += vv[1]; vsum[2] += vv[2]; vsum[3] += vv[3]; }
#pragma unroll
    for (int jj = 0; jj < 15; ++jj) {
      const float a = a_s[kk][jg * 15 + jj];   // wave-uniform broadcast
      acc[jj][0] = fmaf(a, vv[0], acc[jj][0]);
      acc[jj][1] = fmaf(a, vv[1], acc[jj][1]);
      acc[jj][2] = fmaf(a, vv[2], acc[jj][2]);
      acc[jj][3] = fmaf(a, vv[3], acc[jj][3]);
    }
  }

#pragma unroll
  for (int jj = 0; jj < 15; ++jj) {
    const int j = jg * 15 + jj;
    *reinterpret_cast<f32x4*>(
        part + ((size_t)((ks * BATCH + b) * NSEL) + j) * DN + dbase) = acc[jj];
  }
  if (jg == 0)
    *reinterpret_cast<f32x4*>(vpart + ((size_t)(ks * BATCH + b)) * DN + dbase) = vsum;
}

// ---------------- combine v partial sums -> vmean ----------------
__global__ void vmean_combine_kernel(const float* __restrict__ vpart, float* __restrict__ vmean)
{
  int idx = blockIdx.x * 256 + threadIdx.x;   // 0..2047
  if (idx < BATCH * DN) {
    int b = idx / DN, d = idx % DN;
    float s = 0.f;
    for (int c = 0; c < S1KS; ++c) s += vpart[(size_t)(c * BATCH + b) * DN + d];
    vmean[idx] = s * (1.0f / (float)KVN);
  }
}

// ---------------- output: v-mean fill + s1 scatter in one pass ----------------
__global__ __launch_bounds__(256) void out_kernel(
    const float* __restrict__ part, const float* __restrict__ vmean,
    const int* __restrict__ rowslot, float* __restrict__ out)
{
  const int gid = blockIdx.x * 256 + threadIdx.x;   // float4 index, 0..1048575
  const int d4 = gid & 127;
  const int qq = (gid >> 7) & (QN - 1);
  const int b  = gid >> 18;                          // QN*DN/4 = 2^18
  const int slot = rowslot[b * QN + qq];
  f32x4 o;
  if (slot >= 0) {
    o[0] = 0.f; o[1] = 0.f; o[2] = 0.f; o[3] = 0.f;
    for (int ks = 0; ks < S1KS; ++ks) {
      const f32x4 p = reinterpret_cast<const f32x4*>(part)[
          ((size_t)((ks * BATCH + b) * NSEL) + slot) * (DN / 4) + d4];
      o[0] += p[0]; o[1] += p[1]; o[2] += p[2]; o[3] += p[3];
    }
  } else {
    o = reinterpret_cast<const f32x4*>(vmean)[b * (DN / 4) + d4];
  }
  reinterpret_cast<f32x4*>(out)[gid] = o;
}

// ---------------- launcher ----------------
extern "C" void kernel_launch(void* const* d_in, const int* in_sizes, int n_in,
                              void* d_out, int out_size, void* d_ws, size_t ws_size,
                              hipStream_t stream) {
  const float* q    = (const float*)d_in[0];
  const float* k    = (const float*)d_in[1];
  const float* v    = (const float*)d_in[2];
  const int*   sidx = (const int*)d_in[3];
  float* out = (float*)d_out;
  char*  W   = (char*)d_ws;

  // region A [0, 32 MB): bf16 splits (dead after s_mfma_kernel)
  const size_t NEL = (size_t)BATCH * QN * DN;   // 4,194,304
  unsigned short* qh = (unsigned short*)W;
  unsigned short* ql = qh + NEL;
  unsigned short* kh = ql + NEL;
  unsigned short* kl = kh + NEL;

  // region B at +36 MB (clear of the 34.6 MB post-phase region): live across phases
  char* W2 = W + 37748736;
  float* cnt     = (float*)W2;                          // 32 KB
  float* Pmax    = (float*)(W2 + 32768);                // 1 MB
  float* Psum    = (float*)(W2 + 32768 + 1048576);      // 1 MB
  float* Mbuf    = (float*)(W2 + 32768 + 2097152);      // 32 KB
  int*   topidx  = (int*)(W2 + 32768 + 2097152 + 32768);          // 4 KB
  int*   rowslot = (int*)(W2 + 32768 + 2097152 + 32768 + 4096);   // 32 KB
  // ends at ~38.1 MB total; round-2 layout proved ws >= 39.6 MB

  // post-phase-1 buffers aliased into region A (splits dead by then)
  float* attn  = (float*)W;                  // 1.875 MB
  float* part  = (float*)(W + 2097152);      // 64*4*60*512*4 = 31.46 MB -> ends 33.55 MB
  float* vpart = (float*)(W + 33554432);     // 512 KB
  float* vmean = (float*)(W + 34078720);     // 8 KB -> ends ~34.1 MB < 36 MB

  split_kernel<<<dim3(8192), 256, 0, stream>>>(q, k, qh, ql, kh, kl);
  count_kernel<<<dim3(BATCH), 1024, 0, stream>>>(sidx, cnt);
  s_mfma_kernel<<<dim3(512), 256, 0, stream>>>(qh, ql, kh, kl, cnt, Pmax, Psum);
  combine_kernel<<<dim3(BATCH * QN / 256), 256, 0, stream>>>(Pmax, Psum, Mbuf);
  select_kernel<<<dim3(BATCH), 256, 0, stream>>>(Mbuf, topidx, rowslot);
  scores_kernel<<<dim3(KVN / SBN, BATCH), 256, 0, stream>>>(q, topidx, k, attn);
  softmax_kernel<<<dim3(BATCH * NSEL), 256, 0, stream>>>(attn);
  s1_partial_kernel<<<dim3(2, BATCH, S1KS), 256, 0, stream>>>(attn, v, part, vpart);
  vmean_combine_kernel<<<dim3(8), 256, 0, stream>>>(vpart, vmean);
  out_kernel<<<dim3(4096), 256, 0, stream>>>(part, vmean, rowslot, out);
}